// Round 3
// baseline (379.767 us; speedup 1.0000x reference)
//
#include <hip/hip_runtime.h>

#define NBATCH 32
#define NN     1024     // d_model = number of nodes
#define NF     128      // win_size = node feature dim
#define NDG    64       // graph embed dim
#define TOPK   15

// ---------------- workspace layout (bytes) ----------------
#define OFF_QH    ((size_t)0)            // bf16-hi q [32][1024][64]  4 MiB
#define OFF_QL    ((size_t)4194304)      // bf16-lo q                 4 MiB
#define OFF_KH    ((size_t)8388608)      // bf16-hi k                 4 MiB
#define OFF_KL    ((size_t)12582912)     // bf16-lo k                 4 MiB
#define OFF_H     ((size_t)16777216)     // f32 [32][1024][128]      16 MiB
#define OFF_DEG   ((size_t)33554432)     // i32 [32][1024]          128 KiB
#define OFF_BMP   ((size_t)33685504)     // u32 [32][1024][32]        4 MiB
#define OFF_WL    ((size_t)37879808)     // wl_cnt + wl[32767]      128 KiB
#define OFF_TOPK  ((size_t)38010880)     // i32 [32][1024][16]        2 MiB
#define OFF_W64   ((size_t)40108032)     // f64 Wq64[8192], Wk64[8192] 128 KiB
#define OFF_QT64  ((size_t)40239104)     // f64 [32][64][1024]       16 MiB
#define OFF_KT64  ((size_t)57016320)     // f64 [32][64][1024]       16 MiB
#define OFF_TMP   ((size_t)0)            // f32 [32][1024][128]      16 MiB (overlaps QH..KL, dead by then)

typedef short s8v  __attribute__((ext_vector_type(8)));   // 8 bf16 (4 VGPRs) MFMA operand
typedef float f4v  __attribute__((ext_vector_type(4)));   // MFMA accumulator
typedef unsigned short us8v __attribute__((ext_vector_type(8)));

__device__ inline unsigned short bf16_rne(float f) {
    unsigned u = __float_as_uint(f);
    return (unsigned short)((u + 0x7FFFu + ((u >> 16) & 1u)) >> 16);
}
__device__ inline float bf16_tof(unsigned short h) { return __uint_as_float(((unsigned)h) << 16); }

// monotone 22-bit code for f32 score in window [-4, 4): sign + 5-bit biased exp + 16-bit mantissa
__device__ inline unsigned pack22(float s) {
    unsigned u   = __float_as_uint(s);
    int      mag = (int)(u & 0x7FFFFFFFu);
    int      t   = mag - 0x38800000;                 // bias at 2^-14
    t = t < 0 ? 0 : (t > 0x07FFFFFF ? 0x07FFFFFF : t);
    unsigned ts = (unsigned)t >> 6;                  // 21 bits
    return ((int)u < 0) ? (0x1FFFFFu - ts) : (0x200000u | ts);
}
__device__ inline float dec22(unsigned val22) {
    bool pos = (val22 & 0x200000u) != 0;
    unsigned ts = pos ? (val22 & 0x1FFFFFu) : (0x1FFFFFu - (val22 & 0x1FFFFFu));
    float f = __uint_as_float((ts << 6) + 0x38800000u);
    return pos ? f : -f;
}

__global__ __launch_bounds__(256) void k_upcast(const float* __restrict__ Wq,
                                                const float* __restrict__ Wk,
                                                double* __restrict__ Wq64,
                                                double* __restrict__ Wk64) {
    int i = blockIdx.x * 256 + threadIdx.x;  // 0..8191
    Wq64[i] = (double)Wq[i];
    Wk64[i] = (double)Wk[i];
}

// Fused: zero bmp/wl_cnt(+deg harmless) + q,k f64 (repair path) + bf16 hi/lo splits + h = nf@Wg.T.
// grid (16 node-tiles, 2 halves, 32 batch), block 256. lane = node within 64-node tile.
__global__ __launch_bounds__(256) void k_prep(
    const float* __restrict__ x, const float* __restrict__ bq, const float* __restrict__ bk,
    const double* __restrict__ Wq64, const double* __restrict__ Wk64,
    const float* __restrict__ Wg,
    unsigned short* __restrict__ qh, unsigned short* __restrict__ ql,
    unsigned short* __restrict__ kh, unsigned short* __restrict__ kl,
    double* __restrict__ qT64, double* __restrict__ kT64,
    float* __restrict__ h,
    uint4* __restrict__ zbase, int zn)
{
    __shared__ float xs[64 * 129];   // xs[node][f], pad 129 -> conflict-free
    const int t = threadIdx.x;
    const int l = t & 63;
    const int w = t >> 6;
    const int uw = __builtin_amdgcn_readfirstlane(w);
    const int n0 = blockIdx.x * 64;
    const int half = blockIdx.y;
    const int b  = blockIdx.z;

    // --- zero phase (deg + bmp + wl_cnt), grid-stride over 1024 blocks ---
    {
        int lid = ((b * 2 + half) * 16 + blockIdx.x) * 256 + t;   // 0..262143
        for (int i = lid; i < zn; i += 262144)
            zbase[i] = make_uint4(0u, 0u, 0u, 0u);
    }

    {   // xs[node][f] = x[b][f][n0+node]  (coalesced over node)
        const int j = t & 63, fg = t >> 6;
        for (int ff = 0; ff < 32; ++ff) {
            int f = fg + ff * 4;
            xs[j * 129 + f] = x[((size_t)b * NF + f) * NN + n0 + j];
        }
    }
    __syncthreads();

    // --- q/k phase (f64, 8 d-dims per wave) ---
    {
        const int d0 = half * 32 + uw * 8;
        double accq[8], acck[8];
        #pragma unroll
        for (int dd = 0; dd < 8; ++dd) {
            accq[dd] = (double)bq[d0 + dd];
            acck[dd] = (double)bk[d0 + dd];
        }
        for (int fc = 0; fc < 32; ++fc) {
            double dx0 = (double)xs[l * 129 + fc * 4 + 0];
            double dx1 = (double)xs[l * 129 + fc * 4 + 1];
            double dx2 = (double)xs[l * 129 + fc * 4 + 2];
            double dx3 = (double)xs[l * 129 + fc * 4 + 3];
            #pragma unroll
            for (int dd = 0; dd < 8; ++dd) {
                int d = d0 + dd;   // uniform -> scalar loads of weights
                const double* wq = &Wq64[d * NF + fc * 4];
                const double* wk = &Wk64[d * NF + fc * 4];
                accq[dd] += dx0 * wq[0] + dx1 * wq[1] + dx2 * wq[2] + dx3 * wq[3];
                acck[dd] += dx0 * wk[0] + dx1 * wk[1] + dx2 * wk[2] + dx3 * wk[3];
            }
        }
        // f64 [d][n] for repair (coalesced over lane)
        #pragma unroll
        for (int dd = 0; dd < 8; ++dd) {
            size_t idx = ((size_t)b * NDG + d0 + dd) * NN + n0 + l;
            qT64[idx] = accq[dd];
            kT64[idx] = acck[dd];
        }
        // bf16 hi/lo splits, [n][d] layout
        us8v qh0, ql0, kh0, kl0;
        #pragma unroll
        for (int dd = 0; dd < 8; ++dd) {
            float fq = (float)accq[dd];
            unsigned short h1 = bf16_rne(fq);
            unsigned short l1 = bf16_rne(fq - bf16_tof(h1));
            float fk = (float)acck[dd];
            unsigned short h2 = bf16_rne(fk);
            unsigned short l2 = bf16_rne(fk - bf16_tof(h2));
            qh0[dd] = h1; ql0[dd] = l1; kh0[dd] = h2; kl0[dd] = l2;
        }
        size_t nb = ((size_t)b * NN + n0 + l) * NDG + d0;
        *(us8v*)&qh[nb] = qh0;
        *(us8v*)&ql[nb] = ql0;
        *(us8v*)&kh[nb] = kh0;
        *(us8v*)&kl[nb] = kl0;
    }

    // --- h phase (f32, 16 out-features per wave; this block covers f' in [half*64, half*64+64)) ---
    {
        const int fp0 = half * 64 + uw * 16;
        float acc[16];
        #pragma unroll
        for (int i = 0; i < 16; ++i) acc[i] = 0.f;
        for (int fc = 0; fc < 32; ++fc) {
            float x0 = xs[l * 129 + fc * 4 + 0];
            float x1 = xs[l * 129 + fc * 4 + 1];
            float x2 = xs[l * 129 + fc * 4 + 2];
            float x3 = xs[l * 129 + fc * 4 + 3];
            #pragma unroll
            for (int ff = 0; ff < 16; ++ff) {
                const float* wg = &Wg[(fp0 + ff) * NF + fc * 4];
                acc[ff] += x0 * wg[0] + x1 * wg[1] + x2 * wg[2] + x3 * wg[3];
            }
        }
        __syncthreads();   // everyone done reading xs
        #pragma unroll
        for (int ff = 0; ff < 16; ++ff) xs[l * 129 + fp0 + ff] = acc[ff];
        __syncthreads();
        // write h[n][half*64 .. half*64+64) for the 64 nodes
        for (int r = 0; r < 16; ++r) {
            int idx = t + 256 * r;            // 0..4095
            int n = idx >> 6, f = idx & 63;
            h[((size_t)b * NN + n0 + n) * NF + half * 64 + f] = xs[n * 129 + half * 64 + f];
        }
    }
}

// full bitonic sort across 64 lanes, descending (lane 0 = max). 21 substages.
__device__ inline unsigned bsort64(unsigned v, int l) {
    #pragma unroll
    for (int k = 2; k <= 64; k <<= 1) {
        #pragma unroll
        for (int j = k >> 1; j >= 1; j >>= 1) {
            unsigned pv = (unsigned)__shfl_xor((int)v, j, 64);
            bool tm = ((l & k) == 0) == ((l & j) == 0);   // lower lane of desc-run keeps max
            unsigned hi = v > pv ? v : pv;
            unsigned lo = v > pv ? pv : v;
            v = tm ? hi : lo;
        }
    }
    return v;
}

// two independent bitonic sort64 chains interleaved (latency overlap)
__device__ inline void bsort64_2(unsigned& va, unsigned& vb, int l) {
    #pragma unroll
    for (int k = 2; k <= 64; k <<= 1) {
        #pragma unroll
        for (int j = k >> 1; j >= 1; j >>= 1) {
            unsigned pa = (unsigned)__shfl_xor((int)va, j, 64);
            unsigned pb = (unsigned)__shfl_xor((int)vb, j, 64);
            bool tm = ((l & k) == 0) == ((l & j) == 0);
            unsigned ha = va > pa ? va : pa, la = va > pa ? pa : va;
            unsigned hb = vb > pb ? vb : pb, lb = vb > pb ? pb : vb;
            va = tm ? ha : la;
            vb = tm ? hb : lb;
        }
    }
}

// MFMA bf16-split scores, 32 rows/block, B double-buffered, all-resident grid.
// grid (32, 32), block 256 (4 waves): wave w computes cols [256w,256w+256) for all 32 rows,
// then merges rows [8w, 8w+8). 1024 blocks = 4 blocks/CU -> entire grid co-resident (1 generation).
// Statistical prefilter t_r = mean_r + 1.7*std_r; survivors (E~11.4 per row-wave cell, cap 24)
// ballot-compacted into slots[row][wave][24]; per-(row,wave) counts in LDS.
// Merge: gather via count-prefix, one bsort64 per row (paired). Guard C<16 | C>64 | cell>24
// -> dummy set + flagged -> exact f64 k_repair fixes the row (same contract as near-ties).
// deg atomics removed entirely: deg = popcount(bmp row), computed by k_deg after repair.
__global__ __launch_bounds__(256, 4) void k_score(
    const unsigned short* __restrict__ qh, const unsigned short* __restrict__ ql,
    const unsigned short* __restrict__ kh, const unsigned short* __restrict__ kl,
    const float* __restrict__ bk,
    unsigned int* __restrict__ bmp,
    int* __restrict__ topk, int* __restrict__ wl_cnt, int* __restrict__ wl)
{
    __shared__ unsigned slots[32 * 96];   // [row][wave][24], 12 KiB
    __shared__ int      cntw[32 * 4];     // per-(row,wave) survivor count
    const int t = threadIdx.x, l = t & 63, w = t >> 6;   // w in [0,4)
    const int b = blockIdx.y, row0 = blockIdx.x * 32;
    const int m = l & 15, q4 = l >> 4;

    // A fragments: 2 row-groups of 16. A[m][k]: m=lane&15, k=(lane>>4)*8+j
    s8v ah0[2], ah1[2], al0[2], al1[2];
    #pragma unroll
    for (int g = 0; g < 2; ++g) {
        size_t abase = ((size_t)b * NN + row0 + g * 16 + m) * NDG + q4 * 8;
        ah0[g] = *(const s8v*)&qh[abase];
        ah1[g] = *(const s8v*)&qh[abase + 32];
        al0[g] = *(const s8v*)&ql[abase];
        al1[g] = *(const s8v*)&ql[abase + 32];
    }

    // per-row thresholds from q stats: scores ~ N(q.bk/8, |q|^2/64); t = mean + 1.7*std
    unsigned Trow[2][4];
    #pragma unroll
    for (int g = 0; g < 2; ++g) {
        float ssq = 0.f, smn = 0.f;
        #pragma unroll
        for (int j = 0; j < 8; ++j) {
            float q0 = bf16_tof(((us8v)ah0[g])[j]) + bf16_tof(((us8v)al0[g])[j]);
            float q1 = bf16_tof(((us8v)ah1[g])[j]) + bf16_tof(((us8v)al1[g])[j]);
            float b0 = bk[q4 * 8 + j];
            float b1 = bk[q4 * 8 + 32 + j];
            ssq += q0 * q0 + q1 * q1;
            smn += q0 * b0 + q1 * b1;
        }
        ssq += __shfl_xor(ssq, 16, 64); ssq += __shfl_xor(ssq, 32, 64);
        smn += __shfl_xor(smn, 16, 64); smn += __shfl_xor(smn, 32, 64);
        float t_m = 0.125f * smn + 0.2125f * __builtin_sqrtf(ssq);   // 1.7/8 = 0.2125
        unsigned Tm = pack22(t_m) << 10;
        #pragma unroll
        for (int r = 0; r < 4; ++r)
            Trow[g][r] = (unsigned)__shfl((int)Tm, 4 * q4 + r, 64);
    }

    const int colbase = w * 256;
    int basec[2][4] = {{0,0,0,0},{0,0,0,0}};

    // B double-buffer: prefetch tt+1 while computing tt (static indices after full unroll)
    s8v Bh0[2], Bh1[2], Bl0[2], Bl1[2];
    {
        size_t bb = ((size_t)b * NN + colbase + m) * NDG + q4 * 8;
        Bh0[0] = *(const s8v*)&kh[bb];
        Bh1[0] = *(const s8v*)&kh[bb + 32];
        Bl0[0] = *(const s8v*)&kl[bb];
        Bl1[0] = *(const s8v*)&kl[bb + 32];
    }
    #pragma unroll
    for (int tt = 0; tt < 16; ++tt) {
        const int cur = tt & 1;
        if (tt < 15) {
            size_t bb = ((size_t)b * NN + colbase + (tt + 1) * 16 + m) * NDG + q4 * 8;
            Bh0[cur ^ 1] = *(const s8v*)&kh[bb];
            Bh1[cur ^ 1] = *(const s8v*)&kh[bb + 32];
            Bl0[cur ^ 1] = *(const s8v*)&kl[bb];
            Bl1[cur ^ 1] = *(const s8v*)&kl[bb + 32];
        }
        const int col = colbase + tt * 16 + m;
        #pragma unroll
        for (int g = 0; g < 2; ++g) {
            f4v acc = {0.f, 0.f, 0.f, 0.f};
            acc = __builtin_amdgcn_mfma_f32_16x16x32_bf16(al0[g], Bl0[cur], acc, 0, 0, 0);
            acc = __builtin_amdgcn_mfma_f32_16x16x32_bf16(al1[g], Bl1[cur], acc, 0, 0, 0);
            acc = __builtin_amdgcn_mfma_f32_16x16x32_bf16(ah0[g], Bl0[cur], acc, 0, 0, 0);
            acc = __builtin_amdgcn_mfma_f32_16x16x32_bf16(ah1[g], Bl1[cur], acc, 0, 0, 0);
            acc = __builtin_amdgcn_mfma_f32_16x16x32_bf16(al0[g], Bh0[cur], acc, 0, 0, 0);
            acc = __builtin_amdgcn_mfma_f32_16x16x32_bf16(al1[g], Bh1[cur], acc, 0, 0, 0);
            acc = __builtin_amdgcn_mfma_f32_16x16x32_bf16(ah0[g], Bh0[cur], acc, 0, 0, 0);
            acc = __builtin_amdgcn_mfma_f32_16x16x32_bf16(ah1[g], Bh1[cur], acc, 0, 0, 0);
            // C/D: col=lane&15, row=(lane>>4)*4+reg. Ballot-compact survivors per (row, wave).
            #pragma unroll
            for (int r = 0; r < 4; ++r) {
                const int rloc = g * 16 + q4 * 4 + r;      // local row 0..31
                const int grow = row0 + rloc;
                float s = acc[r] * 0.125f;
                unsigned c22 = (col == grow) ? 0u : pack22(s);
                unsigned v = (c22 << 10) | (unsigned)(1023 - col);
                bool p = v >= Trow[g][r];
                unsigned long long mk = __ballot(p);
                unsigned w16 = (unsigned)(mk >> (q4 * 16)) & 0xFFFFu;
                int idx = basec[g][r] + __popc(w16 & ((1u << m) - 1u));
                if (p && idx < 24) slots[rloc * 96 + w * 24 + idx] = v;
                basec[g][r] += __popc(w16);
            }
        }
    }
    // per-(row,wave) raw counts (overflow detectable: >24)
    if (m == 0) {
        #pragma unroll
        for (int g = 0; g < 2; ++g)
            #pragma unroll
            for (int r = 0; r < 4; ++r)
                cntw[(g * 16 + q4 * 4 + r) * 4 + w] = basec[g][r];
    }
    __syncthreads();

    // wave w merges rows [8w, 8w+8) as 4 pairs
    #pragma unroll
    for (int pp = 0; pp < 4; ++pp) {
        const int rA = w * 8 + 2 * pp, rB = rA + 1;
        int a0 = cntw[rA * 4 + 0], a1 = cntw[rA * 4 + 1], a2 = cntw[rA * 4 + 2], a3 = cntw[rA * 4 + 3];
        int b0 = cntw[rB * 4 + 0], b1 = cntw[rB * 4 + 1], b2 = cntw[rB * 4 + 2], b3 = cntw[rB * 4 + 3];
        bool ovA = (a0 > 24) || (a1 > 24) || (a2 > 24) || (a3 > 24);
        bool ovB = (b0 > 24) || (b1 > 24) || (b2 > 24) || (b3 > 24);
        int rawA = a0 + a1 + a2 + a3, rawB = b0 + b1 + b2 + b3;
        a0 = a0 > 24 ? 24 : a0; a1 = a1 > 24 ? 24 : a1; a2 = a2 > 24 ? 24 : a2; a3 = a3 > 24 ? 24 : a3;
        b0 = b0 > 24 ? 24 : b0; b1 = b1 > 24 ? 24 : b1; b2 = b2 > 24 ? 24 : b2; b3 = b3 > 24 ? 24 : b3;
        int PA1 = a0, PA2 = a0 + a1, PA3 = a0 + a1 + a2, CA = PA3 + a3;
        int PB1 = b0, PB2 = b0 + b1, PB3 = b0 + b1 + b2, CB = PB3 + b3;
        bool fbA = ovA || rawA < 16 || rawA > 64;
        bool fbB = ovB || rawB < 16 || rawB > 64;

        int jA = (l >= PA1) + (l >= PA2) + (l >= PA3);
        int jB = (l >= PB1) + (l >= PB2) + (l >= PB3);
        int baseA = jA == 0 ? 0 : (jA == 1 ? PA1 : (jA == 2 ? PA2 : PA3));
        int baseB = jB == 0 ? 0 : (jB == 1 ? PB1 : (jB == 2 ? PB2 : PB3));
        unsigned cva = (l < CA) ? slots[rA * 96 + jA * 24 + (l - baseA)] : 0u;
        unsigned cvb = (l < CB) ? slots[rB * 96 + jB * 24 + (l - baseB)] : 0u;
        bsort64_2(cva, cvb, l);   // lane l = rank-l value (descending)

        #pragma unroll
        for (int rr = 0; rr < 2; ++rr) {
            const int grow = row0 + (rr == 0 ? rA : rB);
            unsigned res   = rr == 0 ? cva : cvb;
            const bool fb  = rr == 0 ? fbA : fbB;

            unsigned r14 = (unsigned)__shfl((int)res, 14, 64);
            unsigned r15 = (unsigned)__shfl((int)res, 15, 64);
            bool flagged;
            if (fb) {
                flagged = true;
            } else {
                float s15 = dec22(r14 >> 10), s16 = dec22(r15 >> 10);
                unsigned e15 = (__float_as_uint(fabsf(s15)) >> 23) & 255u;
                unsigned e16 = (__float_as_uint(fabsf(s16)) >> 23) & 255u;
                unsigned e = e15 > e16 ? e15 : e16;
                float qq = __uint_as_float((e - 17) << 23);    // 22-bit code quantum
                flagged = (s15 - s16) < (4.f * qq + 1e-4f);
            }
            if (l < 15) {
                int col = fb ? ((grow + 1 + l) & 1023)          // dummy distinct non-self set
                             : (1023 - (int)(res & 1023u));
                atomicOr(&bmp[((size_t)b * NN + col) * 32 + (grow >> 5)], 1u << (grow & 31));
                if (flagged) topk[(b * NN + grow) * 16 + l] = col;
            }
            if (l == 0 && flagged) {
                int idx = atomicAdd(wl_cnt, 1);
                if (idx < 32767) wl[idx] = b * NN + grow;
            }
        }
    }
}

// exact f64 re-selection for worklist rows; patches bitmap by set-diff (deg derived later).
// grid 1024, block 64: ~one block per flagged row, fully concurrent; d-loop double-buffered.
__global__ __launch_bounds__(64) void k_repair(
    const double* __restrict__ qT64, const double* __restrict__ kT64,
    const int* __restrict__ topk, const int* __restrict__ wl_cnt, const int* __restrict__ wl,
    unsigned int* __restrict__ bmp)
{
    const int l = threadIdx.x;
    __shared__ double qld[64];
    __shared__ int oldset[15], newset[15];
    const double NEGINF = -__builtin_inf();
    int n = wl_cnt[0]; if (n > 32767) n = 32767;

    for (int i = blockIdx.x; i < n; i += 1024) {
        int rg = wl[i];
        int b = rg >> 10, row = rg & 1023;

        __syncthreads();
        qld[l] = qT64[((size_t)b * NDG + l) * NN + row];
        if (l < 15) oldset[l] = topk[(b * NN + row) * 16 + l];
        __syncthreads();

        double sc[16];
        #pragma unroll
        for (int tt = 0; tt < 16; ++tt) sc[tt] = 0.0;
        const double* kb = &kT64[(size_t)b * NDG * NN];
        double buf[16];
        #pragma unroll
        for (int tt = 0; tt < 16; ++tt) buf[tt] = kb[l + 64 * tt];
        for (int d = 0; d < 64; ++d) {
            double nb[16];
            if (d < 63) {
                const double* kr = kb + (size_t)(d + 1) * NN;
                #pragma unroll
                for (int tt = 0; tt < 16; ++tt) nb[tt] = kr[l + 64 * tt];
            }
            double qd = qld[d];
            #pragma unroll
            for (int tt = 0; tt < 16; ++tt) sc[tt] += qd * buf[tt];
            if (d < 63) {
                #pragma unroll
                for (int tt = 0; tt < 16; ++tt) buf[tt] = nb[tt];
            }
        }
        #pragma unroll
        for (int tt = 0; tt < 16; ++tt) if (l + 64 * tt == row) sc[tt] = NEGINF;

        for (int it = 0; it < 15; ++it) {
            double lv = NEGINF; int lc = 0x7fffffff;
            #pragma unroll
            for (int tt = 0; tt < 16; ++tt)
                if (sc[tt] > lv) { lv = sc[tt]; lc = l + 64 * tt; }
            #pragma unroll
            for (int off = 1; off < 64; off <<= 1) {
                double ov = __shfl_xor(lv, off, 64);
                int    oc = __shfl_xor(lc, off, 64);
                if (ov > lv || (ov == lv && oc < lc)) { lv = ov; lc = oc; }
            }
            #pragma unroll
            for (int tt = 0; tt < 16; ++tt) if (l + 64 * tt == lc) sc[tt] = NEGINF;
            if (l == 0) newset[it] = lc;
        }
        __syncthreads();
        if (l < 15) {
            int cn = newset[l];
            bool found = false;
            #pragma unroll
            for (int j = 0; j < 15; ++j) found = found || (oldset[j] == cn);
            if (!found)
                atomicOr(&bmp[((size_t)b * NN + cn) * 32 + (row >> 5)], 1u << (row & 31));
            int co = oldset[l];
            found = false;
            #pragma unroll
            for (int j = 0; j < 15; ++j) found = found || (newset[j] == co);
            if (!found)
                atomicAnd(&bmp[((size_t)b * NN + co) * 32 + (row >> 5)], ~(1u << (row & 31)));
        }
    }
}

// deg[b][n] = popcount of bmp row (number of rows that selected node n). grid 128, block 256.
__global__ __launch_bounds__(256) void k_deg(const unsigned int* __restrict__ bmp,
                                             int* __restrict__ deg)
{
    int i = blockIdx.x * 256 + threadIdx.x;   // 0..32767 over (b,n)
    const uint4* p = (const uint4*)(bmp + (size_t)i * 32);
    int s = 0;
    #pragma unroll
    for (int j = 0; j < 8; ++j) {
        uint4 v = p[j];
        s += __popc(v.x) + __popc(v.y) + __popc(v.z) + __popc(v.w);
    }
    deg[i] = s;
}

// gather per target via compacted LDS edge list + LDS norm table (dinv folded here).
// grid (1024,32), block 128 (f = thread). Edge loop 4-way unrolled for load ILP.
__global__ __launch_bounds__(128) void k_gather(
    const float* __restrict__ h, const float* __restrict__ bg,
    const int* __restrict__ deg, const unsigned int* __restrict__ bmp,
    float* __restrict__ tmp)
{
    __shared__ int list[1024];
    __shared__ float nrm[1024];
    __shared__ int scnt;
    const int tgt = blockIdx.x, b = blockIdx.y, t = threadIdx.x;
    if (t < 32) {
        unsigned word = bmp[((size_t)b * NN + tgt) * 32 + t];
        int pc = __popc(word);
        int pre = pc;
        #pragma unroll
        for (int d = 1; d < 32; d <<= 1) {
            int o = __shfl_up(pre, d, 32);
            if (t >= d) pre += o;
        }
        if (t == 31) scnt = pre;
        int idx = pre - pc;
        while (word) {
            int s = __ffs(word) - 1;
            word &= word - 1;
            list[idx++] = t * 32 + s;
        }
    }
    __syncthreads();
    const int cnt = scnt;
    for (int e = t; e < cnt; e += 128)
        nrm[e] = rsqrtf((float)(deg[b * NN + list[e]] + 2));
    __syncthreads();
    const int f = t;
    float dt = rsqrtf((float)(deg[b * NN + tgt] + 2));
    float a0 = 0.f, a1 = 0.f, a2 = 0.f, a3 = 0.f;
    int e = 0;
    for (; e + 4 <= cnt; e += 4) {
        a0 += h[((size_t)b * NN + list[e + 0]) * NF + f] * nrm[e + 0];
        a1 += h[((size_t)b * NN + list[e + 1]) * NF + f] * nrm[e + 1];
        a2 += h[((size_t)b * NN + list[e + 2]) * NF + f] * nrm[e + 2];
        a3 += h[((size_t)b * NN + list[e + 3]) * NF + f] * nrm[e + 3];
    }
    for (; e < cnt; ++e)
        a0 += h[((size_t)b * NN + list[e]) * NF + f] * nrm[e];
    float acc = 2.0f * dt * h[((size_t)b * NN + tgt) * NF + f] + ((a0 + a1) + (a2 + a3));
    tmp[((size_t)b * NN + tgt) * NF + f] = bg[f] + dt * acc;
}

// [b][n][f] -> [b][f][n]. grid (32, 4, 32), block 256.
__global__ __launch_bounds__(256) void k_transpose(const float* __restrict__ tmp,
                                                   float* __restrict__ out)
{
    __shared__ float tile[32][33];
    const int t = threadIdx.x;
    const int n0 = blockIdx.x * 32, f0 = blockIdx.y * 32, b = blockIdx.z;
    const int c = t & 31, rb = t >> 5;
    #pragma unroll
    for (int i = 0; i < 4; ++i) {
        int r = rb + i * 8;
        tile[r][c] = tmp[((size_t)b * NN + n0 + r) * NF + f0 + c];
    }
    __syncthreads();
    #pragma unroll
    for (int i = 0; i < 4; ++i) {
        int r = rb + i * 8;
        out[((size_t)b * NF + f0 + r) * NN + n0 + c] = tile[c][r];
    }
}

extern "C" void kernel_launch(void* const* d_in, const int* in_sizes, int n_in,
                              void* d_out, int out_size, void* d_ws, size_t ws_size,
                              hipStream_t stream)
{
    const float* x  = (const float*)d_in[0];
    const float* Wq = (const float*)d_in[1];
    const float* bq = (const float*)d_in[2];
    const float* Wk = (const float*)d_in[3];
    const float* bk = (const float*)d_in[4];
    const float* Wg = (const float*)d_in[5];
    const float* bg = (const float*)d_in[6];
    float* out = (float*)d_out;
    char* ws = (char*)d_ws;

    unsigned short* qh = (unsigned short*)(ws + OFF_QH);
    unsigned short* ql = (unsigned short*)(ws + OFF_QL);
    unsigned short* kh = (unsigned short*)(ws + OFF_KH);
    unsigned short* kl = (unsigned short*)(ws + OFF_KL);
    float*          h   = (float*)(ws + OFF_H);
    int*            deg = (int*)(ws + OFF_DEG);
    unsigned int*   bmp = (unsigned int*)(ws + OFF_BMP);
    int*            wlc = (int*)(ws + OFF_WL);
    int*            wl  = wlc + 1;
    int*            tpk = (int*)(ws + OFF_TOPK);
    double*         Wq64 = (double*)(ws + OFF_W64);
    double*         Wk64 = Wq64 + 8192;
    double*         qT64 = (double*)(ws + OFF_QT64);
    double*         kT64 = (double*)(ws + OFF_KT64);
    float*          tmp  = (float*)(ws + OFF_TMP);

    k_upcast<<<32, 256, 0, stream>>>(Wq, Wk, Wq64, Wk64);
    // zero range: deg + bmp + wl_cnt = 4,325,392 B = 270337 uint4 (done inside k_prep)
    k_prep<<<dim3(16, 2, 32), 256, 0, stream>>>(x, bq, bk, Wq64, Wk64, Wg,
                                                qh, ql, kh, kl, qT64, kT64, h,
                                                (uint4*)(ws + OFF_DEG), 270337);
    k_score<<<dim3(32, 32), 256, 0, stream>>>(qh, ql, kh, kl, bk, bmp, tpk, wlc, wl);
    k_repair<<<1024, 64, 0, stream>>>(qT64, kT64, tpk, wlc, wl, bmp);
    k_deg<<<128, 256, 0, stream>>>(bmp, deg);
    k_gather<<<dim3(1024, 32), 128, 0, stream>>>(h, bg, deg, bmp, tmp);
    k_transpose<<<dim3(32, 4, 32), 256, 0, stream>>>(tmp, out);
}

// Round 5
// 276.365 us; speedup vs baseline: 1.3742x; 1.3742x over previous
//
#include <hip/hip_runtime.h>

#define NBATCH 32
#define NN     1024     // d_model = number of nodes
#define NF     128      // win_size = node feature dim
#define NDG    64       // graph embed dim
#define TOPK   15

// ---------------- workspace layout (bytes) ----------------
#define OFF_QH    ((size_t)0)            // bf16-hi q [32][1024][64]  4 MiB
#define OFF_QL    ((size_t)4194304)      // bf16-lo q                 4 MiB
#define OFF_KH    ((size_t)8388608)      // bf16-hi k                 4 MiB
#define OFF_KL    ((size_t)12582912)     // bf16-lo k                 4 MiB
#define OFF_H     ((size_t)16777216)     // f32 [32][1024][128]      16 MiB
#define OFF_DEG   ((size_t)33554432)     // i32 [32][1024]          128 KiB
#define OFF_BMP   ((size_t)33685504)     // u32 [32][1024][32]        4 MiB
#define OFF_WL    ((size_t)37879808)     // wl_cnt + wl[32767]      128 KiB
#define OFF_TOPK  ((size_t)38010880)     // i32 [32][1024][16]        2 MiB
#define OFF_W64   ((size_t)40108032)     // f64 Wq64[8192], Wk64[8192] 128 KiB
#define OFF_QT64  ((size_t)40239104)     // f64 [32][64][1024]       16 MiB
#define OFF_KT64  ((size_t)57016320)     // f64 [32][64][1024]       16 MiB
#define OFF_TMP   ((size_t)0)            // f32 [32][1024][128]      16 MiB (overlaps QH..KL, dead by then)

typedef short s8v  __attribute__((ext_vector_type(8)));   // 8 bf16 (4 VGPRs) MFMA operand
typedef float f4v  __attribute__((ext_vector_type(4)));   // MFMA accumulator
typedef unsigned short us8v __attribute__((ext_vector_type(8)));

__device__ inline unsigned short bf16_rne(float f) {
    unsigned u = __float_as_uint(f);
    return (unsigned short)((u + 0x7FFFu + ((u >> 16) & 1u)) >> 16);
}
__device__ inline float bf16_tof(unsigned short h) { return __uint_as_float(((unsigned)h) << 16); }

// monotone 22-bit code for f32 score in window [-4, 4): sign + 5-bit biased exp + 16-bit mantissa
__device__ inline unsigned pack22(float s) {
    unsigned u   = __float_as_uint(s);
    int      mag = (int)(u & 0x7FFFFFFFu);
    int      t   = mag - 0x38800000;                 // bias at 2^-14
    t = t < 0 ? 0 : (t > 0x07FFFFFF ? 0x07FFFFFF : t);
    unsigned ts = (unsigned)t >> 6;                  // 21 bits
    return ((int)u < 0) ? (0x1FFFFFu - ts) : (0x200000u | ts);
}
__device__ inline float dec22(unsigned val22) {
    bool pos = (val22 & 0x200000u) != 0;
    unsigned ts = pos ? (val22 & 0x1FFFFFu) : (0x1FFFFFu - (val22 & 0x1FFFFFu));
    float f = __uint_as_float((ts << 6) + 0x38800000u);
    return pos ? f : -f;
}

__global__ __launch_bounds__(256) void k_upcast(const float* __restrict__ Wq,
                                                const float* __restrict__ Wk,
                                                double* __restrict__ Wq64,
                                                double* __restrict__ Wk64) {
    int i = blockIdx.x * 256 + threadIdx.x;  // 0..8191
    Wq64[i] = (double)Wq[i];
    Wk64[i] = (double)Wk[i];
}

// Fused: zero bmp/wl_cnt(+deg harmless) + q,k f64 (repair path) + bf16 hi/lo splits + h = nf@Wg.T.
// grid (16 node-tiles, 2 halves, 32 batch), block 256. lane = node within 64-node tile.
__global__ __launch_bounds__(256) void k_prep(
    const float* __restrict__ x, const float* __restrict__ bq, const float* __restrict__ bk,
    const double* __restrict__ Wq64, const double* __restrict__ Wk64,
    const float* __restrict__ Wg,
    unsigned short* __restrict__ qh, unsigned short* __restrict__ ql,
    unsigned short* __restrict__ kh, unsigned short* __restrict__ kl,
    double* __restrict__ qT64, double* __restrict__ kT64,
    float* __restrict__ h,
    uint4* __restrict__ zbase, int zn)
{
    __shared__ float xs[64 * 129];   // xs[node][f], pad 129 -> conflict-free
    const int t = threadIdx.x;
    const int l = t & 63;
    const int w = t >> 6;
    const int uw = __builtin_amdgcn_readfirstlane(w);
    const int n0 = blockIdx.x * 64;
    const int half = blockIdx.y;
    const int b  = blockIdx.z;

    // --- zero phase (deg + bmp + wl_cnt), grid-stride over 1024 blocks ---
    {
        int lid = ((b * 2 + half) * 16 + blockIdx.x) * 256 + t;   // 0..262143
        for (int i = lid; i < zn; i += 262144)
            zbase[i] = make_uint4(0u, 0u, 0u, 0u);
    }

    {   // xs[node][f] = x[b][f][n0+node]  (coalesced over node)
        const int j = t & 63, fg = t >> 6;
        for (int ff = 0; ff < 32; ++ff) {
            int f = fg + ff * 4;
            xs[j * 129 + f] = x[((size_t)b * NF + f) * NN + n0 + j];
        }
    }
    __syncthreads();

    // --- q/k phase (f64, 8 d-dims per wave) ---
    {
        const int d0 = half * 32 + uw * 8;
        double accq[8], acck[8];
        #pragma unroll
        for (int dd = 0; dd < 8; ++dd) {
            accq[dd] = (double)bq[d0 + dd];
            acck[dd] = (double)bk[d0 + dd];
        }
        for (int fc = 0; fc < 32; ++fc) {
            double dx0 = (double)xs[l * 129 + fc * 4 + 0];
            double dx1 = (double)xs[l * 129 + fc * 4 + 1];
            double dx2 = (double)xs[l * 129 + fc * 4 + 2];
            double dx3 = (double)xs[l * 129 + fc * 4 + 3];
            #pragma unroll
            for (int dd = 0; dd < 8; ++dd) {
                int d = d0 + dd;   // uniform -> scalar loads of weights
                const double* wq = &Wq64[d * NF + fc * 4];
                const double* wk = &Wk64[d * NF + fc * 4];
                accq[dd] += dx0 * wq[0] + dx1 * wq[1] + dx2 * wq[2] + dx3 * wq[3];
                acck[dd] += dx0 * wk[0] + dx1 * wk[1] + dx2 * wk[2] + dx3 * wk[3];
            }
        }
        // f64 [d][n] for repair (coalesced over lane)
        #pragma unroll
        for (int dd = 0; dd < 8; ++dd) {
            size_t idx = ((size_t)b * NDG + d0 + dd) * NN + n0 + l;
            qT64[idx] = accq[dd];
            kT64[idx] = acck[dd];
        }
        // bf16 hi/lo splits, [n][d] layout
        us8v qh0, ql0, kh0, kl0;
        #pragma unroll
        for (int dd = 0; dd < 8; ++dd) {
            float fq = (float)accq[dd];
            unsigned short h1 = bf16_rne(fq);
            unsigned short l1 = bf16_rne(fq - bf16_tof(h1));
            float fk = (float)acck[dd];
            unsigned short h2 = bf16_rne(fk);
            unsigned short l2 = bf16_rne(fk - bf16_tof(h2));
            qh0[dd] = h1; ql0[dd] = l1; kh0[dd] = h2; kl0[dd] = l2;
        }
        size_t nb = ((size_t)b * NN + n0 + l) * NDG + d0;
        *(us8v*)&qh[nb] = qh0;
        *(us8v*)&ql[nb] = ql0;
        *(us8v*)&kh[nb] = kh0;
        *(us8v*)&kl[nb] = kl0;
    }

    // --- h phase (f32, 16 out-features per wave; this block covers f' in [half*64, half*64+64)) ---
    {
        const int fp0 = half * 64 + uw * 16;
        float acc[16];
        #pragma unroll
        for (int i = 0; i < 16; ++i) acc[i] = 0.f;
        for (int fc = 0; fc < 32; ++fc) {
            float x0 = xs[l * 129 + fc * 4 + 0];
            float x1 = xs[l * 129 + fc * 4 + 1];
            float x2 = xs[l * 129 + fc * 4 + 2];
            float x3 = xs[l * 129 + fc * 4 + 3];
            #pragma unroll
            for (int ff = 0; ff < 16; ++ff) {
                const float* wg = &Wg[(fp0 + ff) * NF + fc * 4];
                acc[ff] += x0 * wg[0] + x1 * wg[1] + x2 * wg[2] + x3 * wg[3];
            }
        }
        __syncthreads();   // everyone done reading xs
        #pragma unroll
        for (int ff = 0; ff < 16; ++ff) xs[l * 129 + fp0 + ff] = acc[ff];
        __syncthreads();
        // write h[n][half*64 .. half*64+64) for the 64 nodes
        for (int r = 0; r < 16; ++r) {
            int idx = t + 256 * r;            // 0..4095
            int n = idx >> 6, f = idx & 63;
            h[((size_t)b * NN + n0 + n) * NF + half * 64 + f] = xs[n * 129 + half * 64 + f];
        }
    }
}

// two independent bitonic sort64 chains interleaved (latency overlap); descending, lane l = rank l
__device__ inline void bsort64_2(unsigned& va, unsigned& vb, int l) {
    #pragma unroll
    for (int k = 2; k <= 64; k <<= 1) {
        #pragma unroll
        for (int j = k >> 1; j >= 1; j >>= 1) {
            unsigned pa = (unsigned)__shfl_xor((int)va, j, 64);
            unsigned pb = (unsigned)__shfl_xor((int)vb, j, 64);
            bool tm = ((l & k) == 0) == ((l & j) == 0);
            unsigned ha = va > pa ? va : pa, la = va > pa ? pa : va;
            unsigned hb = vb > pb ? vb : pb, lb = vb > pb ? pb : vb;
            va = tm ? ha : la;
            vb = tm ? hb : lb;
        }
    }
}

// MFMA bf16-split scores, 32 rows/block, B double-buffered, all-resident grid.
// grid (32, 32), block 256 (4 waves): wave w computes cols [256w,256w+256) for all 32 rows,
// then merges rows [8w, 8w+8). 1024 blocks = 4 blocks/CU -> entire grid co-resident.
// Statistical prefilter t_r = mean_r + 1.8*std_r; E[raw] = 36.7, P(raw>64) ~ 1.5e-6,
// P(raw<16) ~ 2.5e-4; survivors ballot-compacted into slots[row][wave][24].
// Guard raw<16 | raw>64 | cell>24 -> dummy set + flagged -> exact f64 k_repair fixes the row.
// deg atomics removed entirely: deg = popcount(bmp row), computed by k_deg after repair.
__global__ __launch_bounds__(256) void k_score(
    const unsigned short* __restrict__ qh, const unsigned short* __restrict__ ql,
    const unsigned short* __restrict__ kh, const unsigned short* __restrict__ kl,
    const float* __restrict__ bk,
    unsigned int* __restrict__ bmp,
    int* __restrict__ topk, int* __restrict__ wl_cnt, int* __restrict__ wl)
{
    __shared__ unsigned slots[32 * 96];   // [row][wave][24], 12 KiB
    __shared__ int      cntw[32 * 4];     // per-(row,wave) survivor count
    const int t = threadIdx.x, l = t & 63, w = t >> 6;   // w in [0,4)
    const int b = blockIdx.y, row0 = blockIdx.x * 32;
    const int m = l & 15, q4 = l >> 4;

    // A fragments: 2 row-groups of 16. A[m][k]: m=lane&15, k=(lane>>4)*8+j
    s8v ah0[2], ah1[2], al0[2], al1[2];
    #pragma unroll
    for (int g = 0; g < 2; ++g) {
        size_t abase = ((size_t)b * NN + row0 + g * 16 + m) * NDG + q4 * 8;
        ah0[g] = *(const s8v*)&qh[abase];
        ah1[g] = *(const s8v*)&qh[abase + 32];
        al0[g] = *(const s8v*)&ql[abase];
        al1[g] = *(const s8v*)&ql[abase + 32];
    }

    // per-row thresholds from q stats: scores ~ N(q.bk/8, |q|^2/64); t = mean + 1.8*std
    unsigned Trow[2][4];
    #pragma unroll
    for (int g = 0; g < 2; ++g) {
        float ssq = 0.f, smn = 0.f;
        #pragma unroll
        for (int j = 0; j < 8; ++j) {
            float q0 = bf16_tof(((us8v)ah0[g])[j]) + bf16_tof(((us8v)al0[g])[j]);
            float q1 = bf16_tof(((us8v)ah1[g])[j]) + bf16_tof(((us8v)al1[g])[j]);
            float b0 = bk[q4 * 8 + j];
            float b1 = bk[q4 * 8 + 32 + j];
            ssq += q0 * q0 + q1 * q1;
            smn += q0 * b0 + q1 * b1;
        }
        ssq += __shfl_xor(ssq, 16, 64); ssq += __shfl_xor(ssq, 32, 64);
        smn += __shfl_xor(smn, 16, 64); smn += __shfl_xor(smn, 32, 64);
        float t_m = 0.125f * smn + 0.2250f * __builtin_sqrtf(ssq);   // 1.8/8 = 0.225
        unsigned Tm = pack22(t_m) << 10;
        #pragma unroll
        for (int r = 0; r < 4; ++r)
            Trow[g][r] = (unsigned)__shfl((int)Tm, 4 * q4 + r, 64);
    }

    const int colbase = w * 256;
    int basec[2][4] = {{0,0,0,0},{0,0,0,0}};

    // B double-buffer: prefetch tt+1 while computing tt (static indices after full unroll)
    s8v Bh0[2], Bh1[2], Bl0[2], Bl1[2];
    {
        size_t bb = ((size_t)b * NN + colbase + m) * NDG + q4 * 8;
        Bh0[0] = *(const s8v*)&kh[bb];
        Bh1[0] = *(const s8v*)&kh[bb + 32];
        Bl0[0] = *(const s8v*)&kl[bb];
        Bl1[0] = *(const s8v*)&kl[bb + 32];
    }
    #pragma unroll
    for (int tt = 0; tt < 16; ++tt) {
        const int cur = tt & 1;
        if (tt < 15) {
            size_t bb = ((size_t)b * NN + colbase + (tt + 1) * 16 + m) * NDG + q4 * 8;
            Bh0[cur ^ 1] = *(const s8v*)&kh[bb];
            Bh1[cur ^ 1] = *(const s8v*)&kh[bb + 32];
            Bl0[cur ^ 1] = *(const s8v*)&kl[bb];
            Bl1[cur ^ 1] = *(const s8v*)&kl[bb + 32];
        }
        const int col = colbase + tt * 16 + m;
        #pragma unroll
        for (int g = 0; g < 2; ++g) {
            f4v acc = {0.f, 0.f, 0.f, 0.f};
            acc = __builtin_amdgcn_mfma_f32_16x16x32_bf16(al0[g], Bl0[cur], acc, 0, 0, 0);
            acc = __builtin_amdgcn_mfma_f32_16x16x32_bf16(al1[g], Bl1[cur], acc, 0, 0, 0);
            acc = __builtin_amdgcn_mfma_f32_16x16x32_bf16(ah0[g], Bl0[cur], acc, 0, 0, 0);
            acc = __builtin_amdgcn_mfma_f32_16x16x32_bf16(ah1[g], Bl1[cur], acc, 0, 0, 0);
            acc = __builtin_amdgcn_mfma_f32_16x16x32_bf16(al0[g], Bh0[cur], acc, 0, 0, 0);
            acc = __builtin_amdgcn_mfma_f32_16x16x32_bf16(al1[g], Bh1[cur], acc, 0, 0, 0);
            acc = __builtin_amdgcn_mfma_f32_16x16x32_bf16(ah0[g], Bh0[cur], acc, 0, 0, 0);
            acc = __builtin_amdgcn_mfma_f32_16x16x32_bf16(ah1[g], Bh1[cur], acc, 0, 0, 0);
            // C/D: col=lane&15, row=(lane>>4)*4+reg. Ballot-compact survivors per (row, wave).
            #pragma unroll
            for (int r = 0; r < 4; ++r) {
                const int rloc = g * 16 + q4 * 4 + r;      // local row 0..31
                const int grow = row0 + rloc;
                float s = acc[r] * 0.125f;
                unsigned c22 = (col == grow) ? 0u : pack22(s);
                unsigned v = (c22 << 10) | (unsigned)(1023 - col);
                bool p = v >= Trow[g][r];
                unsigned long long mk = __ballot(p);
                unsigned w16 = (unsigned)(mk >> (q4 * 16)) & 0xFFFFu;
                int idx = basec[g][r] + __popc(w16 & ((1u << m) - 1u));
                if (p && idx < 24) slots[rloc * 96 + w * 24 + idx] = v;
                basec[g][r] += __popc(w16);
            }
        }
    }
    // per-(row,wave) raw counts (overflow detectable: >24)
    if (m == 0) {
        #pragma unroll
        for (int g = 0; g < 2; ++g)
            #pragma unroll
            for (int r = 0; r < 4; ++r)
                cntw[(g * 16 + q4 * 4 + r) * 4 + w] = basec[g][r];
    }
    __syncthreads();

    // wave w merges rows [8w, 8w+8) as 4 pairs
    #pragma unroll
    for (int pp = 0; pp < 4; ++pp) {
        const int rA = w * 8 + 2 * pp, rB = rA + 1;
        int a0 = cntw[rA * 4 + 0], a1 = cntw[rA * 4 + 1], a2 = cntw[rA * 4 + 2], a3 = cntw[rA * 4 + 3];
        int b0 = cntw[rB * 4 + 0], b1 = cntw[rB * 4 + 1], b2 = cntw[rB * 4 + 2], b3 = cntw[rB * 4 + 3];
        bool ovA = (a0 > 24) || (a1 > 24) || (a2 > 24) || (a3 > 24);
        bool ovB = (b0 > 24) || (b1 > 24) || (b2 > 24) || (b3 > 24);
        int rawA = a0 + a1 + a2 + a3, rawB = b0 + b1 + b2 + b3;
        a0 = a0 > 24 ? 24 : a0; a1 = a1 > 24 ? 24 : a1; a2 = a2 > 24 ? 24 : a2; a3 = a3 > 24 ? 24 : a3;
        b0 = b0 > 24 ? 24 : b0; b1 = b1 > 24 ? 24 : b1; b2 = b2 > 24 ? 24 : b2; b3 = b3 > 24 ? 24 : b3;
        int PA1 = a0, PA2 = a0 + a1, PA3 = a0 + a1 + a2, CA = PA3 + a3;
        int PB1 = b0, PB2 = b0 + b1, PB3 = b0 + b1 + b2, CB = PB3 + b3;
        bool fbA = ovA || rawA < 16 || rawA > 64;
        bool fbB = ovB || rawB < 16 || rawB > 64;

        int jA = (l >= PA1) + (l >= PA2) + (l >= PA3);
        int jB = (l >= PB1) + (l >= PB2) + (l >= PB3);
        int baseA = jA == 0 ? 0 : (jA == 1 ? PA1 : (jA == 2 ? PA2 : PA3));
        int baseB = jB == 0 ? 0 : (jB == 1 ? PB1 : (jB == 2 ? PB2 : PB3));
        unsigned cva = (l < CA) ? slots[rA * 96 + jA * 24 + (l - baseA)] : 0u;
        unsigned cvb = (l < CB) ? slots[rB * 96 + jB * 24 + (l - baseB)] : 0u;
        bsort64_2(cva, cvb, l);   // lane l = rank-l value (descending)

        #pragma unroll
        for (int rr = 0; rr < 2; ++rr) {
            const int grow = row0 + (rr == 0 ? rA : rB);
            unsigned res   = rr == 0 ? cva : cvb;
            const bool fb  = rr == 0 ? fbA : fbB;

            unsigned r14 = (unsigned)__shfl((int)res, 14, 64);
            unsigned r15 = (unsigned)__shfl((int)res, 15, 64);
            bool flagged;
            if (fb) {
                flagged = true;
            } else {
                float s15 = dec22(r14 >> 10), s16 = dec22(r15 >> 10);
                unsigned e15 = (__float_as_uint(fabsf(s15)) >> 23) & 255u;
                unsigned e16 = (__float_as_uint(fabsf(s16)) >> 23) & 255u;
                unsigned e = e15 > e16 ? e15 : e16;
                float qq = __uint_as_float((e - 17) << 23);    // 22-bit code quantum
                flagged = (s15 - s16) < (4.f * qq + 1e-4f);
            }
            if (l < 15) {
                int col = fb ? ((grow + 1 + l) & 1023)          // dummy distinct non-self set
                             : (1023 - (int)(res & 1023u));
                atomicOr(&bmp[((size_t)b * NN + col) * 32 + (grow >> 5)], 1u << (grow & 31));
                if (flagged) topk[(b * NN + grow) * 16 + l] = col;
            }
            if (l == 0 && flagged) {
                int idx = atomicAdd(wl_cnt, 1);
                if (idx < 32767) wl[idx] = b * NN + grow;
            }
        }
    }
}

// exact f64 re-selection for worklist rows; patches bitmap by set-diff (deg derived later).
// grid 1024, block 256 (4 waves per ROW, cooperative): wave w handles cols [256w, 256w+256),
// 4 score chains per lane (scalars -> registers, no spill), scalar double-buffer over d.
// Selection: 15 block-wide argmax iterations (wave shfl-reduce -> 4 LDS candidates -> pick).
__global__ __launch_bounds__(256) void k_repair(
    const double* __restrict__ qT64, const double* __restrict__ kT64,
    const int* __restrict__ topk, const int* __restrict__ wl_cnt, const int* __restrict__ wl,
    unsigned int* __restrict__ bmp)
{
    const int t = threadIdx.x, l = t & 63, w = t >> 6;
    __shared__ double qld[64];
    __shared__ double cmax[4];
    __shared__ int    cidx[4];
    __shared__ int    oldset[15], newset[15];
    const double NEGINF = -__builtin_inf();
    int n = wl_cnt[0]; if (n > 32767) n = 32767;

    for (int i = blockIdx.x; i < n; i += 1024) {
        int rg = wl[i];
        int b = rg >> 10, row = rg & 1023;

        __syncthreads();   // guard qld/newset reuse across grid-stride iterations
        if (t < 64) qld[t] = qT64[((size_t)b * NDG + t) * NN + row];
        if (t < 15) oldset[t] = topk[(b * NN + row) * 16 + t];
        __syncthreads();

        const double* kb = &kT64[(size_t)b * NDG * NN];
        const int base = l + 256 * w;
        const int c0 = base, c1 = base + 64, c2 = base + 128, c3 = base + 192;
        double s0 = 0.0, s1 = 0.0, s2 = 0.0, s3 = 0.0;
        double b0 = kb[c0], b1 = kb[c1], b2 = kb[c2], b3 = kb[c3];
        for (int d = 0; d < 64; ++d) {
            double n0, n1, n2, n3;
            if (d < 63) {
                const double* kr = kb + (size_t)(d + 1) * NN;
                n0 = kr[c0]; n1 = kr[c1]; n2 = kr[c2]; n3 = kr[c3];
            }
            double qd = qld[d];
            s0 += qd * b0; s1 += qd * b1; s2 += qd * b2; s3 += qd * b3;
            if (d < 63) { b0 = n0; b1 = n1; b2 = n2; b3 = n3; }
        }
        if (c0 == row) s0 = NEGINF;
        if (c1 == row) s1 = NEGINF;
        if (c2 == row) s2 = NEGINF;
        if (c3 == row) s3 = NEGINF;

        for (int it = 0; it < 15; ++it) {
            double lv = NEGINF; int lc = 0x7fffffff;
            if (s0 > lv) { lv = s0; lc = c0; }
            if (s1 > lv) { lv = s1; lc = c1; }
            if (s2 > lv) { lv = s2; lc = c2; }
            if (s3 > lv) { lv = s3; lc = c3; }
            #pragma unroll
            for (int off = 1; off < 64; off <<= 1) {
                double ov = __shfl_xor(lv, off, 64);
                int    oc = __shfl_xor(lc, off, 64);
                if (ov > lv || (ov == lv && oc < lc)) { lv = ov; lc = oc; }
            }
            if (l == 0) { cmax[w] = lv; cidx[w] = lc; }
            __syncthreads();
            if (t == 0) {
                double bv = cmax[0]; int bc = cidx[0];
                #pragma unroll
                for (int ww = 1; ww < 4; ++ww)
                    if (cmax[ww] > bv || (cmax[ww] == bv && cidx[ww] < bc)) { bv = cmax[ww]; bc = cidx[ww]; }
                newset[it] = bc;
            }
            __syncthreads();
            int bc = newset[it];
            if (c0 == bc) s0 = NEGINF;
            if (c1 == bc) s1 = NEGINF;
            if (c2 == bc) s2 = NEGINF;
            if (c3 == bc) s3 = NEGINF;
        }

        if (t < 15) {
            int cn = newset[t];
            bool found = false;
            #pragma unroll
            for (int j = 0; j < 15; ++j) found = found || (oldset[j] == cn);
            if (!found)
                atomicOr(&bmp[((size_t)b * NN + cn) * 32 + (row >> 5)], 1u << (row & 31));
            int co = oldset[t];
            found = false;
            #pragma unroll
            for (int j = 0; j < 15; ++j) found = found || (newset[j] == co);
            if (!found)
                atomicAnd(&bmp[((size_t)b * NN + co) * 32 + (row >> 5)], ~(1u << (row & 31)));
        }
    }
}

// deg[b][n] = popcount of bmp row (number of rows that selected node n). grid 128, block 256.
__global__ __launch_bounds__(256) void k_deg(const unsigned int* __restrict__ bmp,
                                             int* __restrict__ deg)
{
    int i = blockIdx.x * 256 + threadIdx.x;   // 0..32767 over (b,n)
    const uint4* p = (const uint4*)(bmp + (size_t)i * 32);
    int s = 0;
    #pragma unroll
    for (int j = 0; j < 8; ++j) {
        uint4 v = p[j];
        s += __popc(v.x) + __popc(v.y) + __popc(v.z) + __popc(v.w);
    }
    deg[i] = s;
}

// gather per target via compacted LDS edge list + LDS norm table (dinv folded here).
// grid (1024,32), block 128 (f = thread). Edge loop 4-way unrolled for load ILP.
__global__ __launch_bounds__(128) void k_gather(
    const float* __restrict__ h, const float* __restrict__ bg,
    const int* __restrict__ deg, const unsigned int* __restrict__ bmp,
    float* __restrict__ tmp)
{
    __shared__ int list[1024];
    __shared__ float nrm[1024];
    __shared__ int scnt;
    const int tgt = blockIdx.x, b = blockIdx.y, t = threadIdx.x;
    if (t < 32) {
        unsigned word = bmp[((size_t)b * NN + tgt) * 32 + t];
        int pc = __popc(word);
        int pre = pc;
        #pragma unroll
        for (int d = 1; d < 32; d <<= 1) {
            int o = __shfl_up(pre, d, 32);
            if (t >= d) pre += o;
        }
        if (t == 31) scnt = pre;
        int idx = pre - pc;
        while (word) {
            int s = __ffs(word) - 1;
            word &= word - 1;
            list[idx++] = t * 32 + s;
        }
    }
    __syncthreads();
    const int cnt = scnt;
    for (int e = t; e < cnt; e += 128)
        nrm[e] = rsqrtf((float)(deg[b * NN + list[e]] + 2));
    __syncthreads();
    const int f = t;
    float dt = rsqrtf((float)(deg[b * NN + tgt] + 2));
    float a0 = 0.f, a1 = 0.f, a2 = 0.f, a3 = 0.f;
    int e = 0;
    for (; e + 4 <= cnt; e += 4) {
        a0 += h[((size_t)b * NN + list[e + 0]) * NF + f] * nrm[e + 0];
        a1 += h[((size_t)b * NN + list[e + 1]) * NF + f] * nrm[e + 1];
        a2 += h[((size_t)b * NN + list[e + 2]) * NF + f] * nrm[e + 2];
        a3 += h[((size_t)b * NN + list[e + 3]) * NF + f] * nrm[e + 3];
    }
    for (; e < cnt; ++e)
        a0 += h[((size_t)b * NN + list[e]) * NF + f] * nrm[e];
    float acc = 2.0f * dt * h[((size_t)b * NN + tgt) * NF + f] + ((a0 + a1) + (a2 + a3));
    tmp[((size_t)b * NN + tgt) * NF + f] = bg[f] + dt * acc;
}

// [b][n][f] -> [b][f][n]. grid (32, 4, 32), block 256.
__global__ __launch_bounds__(256) void k_transpose(const float* __restrict__ tmp,
                                                   float* __restrict__ out)
{
    __shared__ float tile[32][33];
    const int t = threadIdx.x;
    const int n0 = blockIdx.x * 32, f0 = blockIdx.y * 32, b = blockIdx.z;
    const int c = t & 31, rb = t >> 5;
    #pragma unroll
    for (int i = 0; i < 4; ++i) {
        int r = rb + i * 8;
        tile[r][c] = tmp[((size_t)b * NN + n0 + r) * NF + f0 + c];
    }
    __syncthreads();
    #pragma unroll
    for (int i = 0; i < 4; ++i) {
        int r = rb + i * 8;
        out[((size_t)b * NF + f0 + r) * NN + n0 + c] = tile[c][r];
    }
}

extern "C" void kernel_launch(void* const* d_in, const int* in_sizes, int n_in,
                              void* d_out, int out_size, void* d_ws, size_t ws_size,
                              hipStream_t stream)
{
    const float* x  = (const float*)d_in[0];
    const float* Wq = (const float*)d_in[1];
    const float* bq = (const float*)d_in[2];
    const float* Wk = (const float*)d_in[3];
    const float* bk = (const float*)d_in[4];
    const float* Wg = (const float*)d_in[5];
    const float* bg = (const float*)d_in[6];
    float* out = (float*)d_out;
    char* ws = (char*)d_ws;

    unsigned short* qh = (unsigned short*)(ws + OFF_QH);
    unsigned short* ql = (unsigned short*)(ws + OFF_QL);
    unsigned short* kh = (unsigned short*)(ws + OFF_KH);
    unsigned short* kl = (unsigned short*)(ws + OFF_KL);
    float*          h   = (float*)(ws + OFF_H);
    int*            deg = (int*)(ws + OFF_DEG);
    unsigned int*   bmp = (unsigned int*)(ws + OFF_BMP);
    int*            wlc = (int*)(ws + OFF_WL);
    int*            wl  = wlc + 1;
    int*            tpk = (int*)(ws + OFF_TOPK);
    double*         Wq64 = (double*)(ws + OFF_W64);
    double*         Wk64 = Wq64 + 8192;
    double*         qT64 = (double*)(ws + OFF_QT64);
    double*         kT64 = (double*)(ws + OFF_KT64);
    float*          tmp  = (float*)(ws + OFF_TMP);

    k_upcast<<<32, 256, 0, stream>>>(Wq, Wk, Wq64, Wk64);
    // zero range: deg + bmp + wl_cnt = 4,325,392 B = 270337 uint4 (done inside k_prep)
    k_prep<<<dim3(16, 2, 32), 256, 0, stream>>>(x, bq, bk, Wq64, Wk64, Wg,
                                                qh, ql, kh, kl, qT64, kT64, h,
                                                (uint4*)(ws + OFF_DEG), 270337);
    k_score<<<dim3(32, 32), 256, 0, stream>>>(qh, ql, kh, kl, bk, bmp, tpk, wlc, wl);
    k_repair<<<1024, 256, 0, stream>>>(qT64, kT64, tpk, wlc, wl, bmp);
    k_deg<<<128, 256, 0, stream>>>(bmp, deg);
    k_gather<<<dim3(1024, 32), 128, 0, stream>>>(h, bg, deg, bmp, tmp);
    k_transpose<<<dim3(32, 4, 32), 256, 0, stream>>>(tmp, out);
}

// Round 6
// 271.496 us; speedup vs baseline: 1.3988x; 1.0179x over previous
//
#include <hip/hip_runtime.h>

#define NBATCH 32
#define NN     1024     // d_model = number of nodes
#define NF     128      // win_size = node feature dim
#define NDG    64       // graph embed dim
#define TOPK   15

// ---------------- workspace layout (bytes) ----------------
#define OFF_QH    ((size_t)0)            // bf16-hi q [32][1024][64]  4 MiB
#define OFF_QL    ((size_t)4194304)      // bf16-lo q                 4 MiB
#define OFF_KH    ((size_t)8388608)      // bf16-hi k                 4 MiB
#define OFF_KL    ((size_t)12582912)     // bf16-lo k                 4 MiB
#define OFF_H     ((size_t)16777216)     // f32 [32][1024][128]      16 MiB
#define OFF_DEG   ((size_t)33554432)     // i32 [32][1024]          128 KiB
#define OFF_BMP   ((size_t)33685504)     // u32 [32][1024][32]        4 MiB
#define OFF_WL    ((size_t)37879808)     // wl_cnt + wl[32767]      128 KiB
#define OFF_TOPK  ((size_t)38010880)     // i32 [32][1024][16]        2 MiB
#define OFF_W64   ((size_t)40108032)     // f64 Wq64[8192], Wk64[8192] 128 KiB
#define OFF_QT64  ((size_t)40239104)     // f64 [32][64][1024]       16 MiB
#define OFF_KT64  ((size_t)57016320)     // f64 [32][64][1024]       16 MiB
#define OFF_TMP   ((size_t)0)            // f32 [32][1024][128]      16 MiB (overlaps QH..KL, dead by then)

typedef short s8v  __attribute__((ext_vector_type(8)));   // 8 bf16 (4 VGPRs) MFMA operand
typedef float f4v  __attribute__((ext_vector_type(4)));   // MFMA accumulator
typedef unsigned short us8v __attribute__((ext_vector_type(8)));

__device__ inline unsigned short bf16_rne(float f) {
    unsigned u = __float_as_uint(f);
    return (unsigned short)((u + 0x7FFFu + ((u >> 16) & 1u)) >> 16);
}
__device__ inline float bf16_tof(unsigned short h) { return __uint_as_float(((unsigned)h) << 16); }

// monotone 22-bit code for f32 score in window [-4, 4): sign + 5-bit biased exp + 16-bit mantissa
__device__ inline unsigned pack22(float s) {
    unsigned u   = __float_as_uint(s);
    int      mag = (int)(u & 0x7FFFFFFFu);
    int      t   = mag - 0x38800000;                 // bias at 2^-14
    t = t < 0 ? 0 : (t > 0x07FFFFFF ? 0x07FFFFFF : t);
    unsigned ts = (unsigned)t >> 6;                  // 21 bits
    return ((int)u < 0) ? (0x1FFFFFu - ts) : (0x200000u | ts);
}
__device__ inline float dec22(unsigned val22) {
    bool pos = (val22 & 0x200000u) != 0;
    unsigned ts = pos ? (val22 & 0x1FFFFFu) : (0x1FFFFFu - (val22 & 0x1FFFFFu));
    float f = __uint_as_float((ts << 6) + 0x38800000u);
    return pos ? f : -f;
}

__global__ __launch_bounds__(256) void k_upcast(const float* __restrict__ Wq,
                                                const float* __restrict__ Wk,
                                                double* __restrict__ Wq64,
                                                double* __restrict__ Wk64) {
    int i = blockIdx.x * 256 + threadIdx.x;  // 0..8191
    Wq64[i] = (double)Wq[i];
    Wk64[i] = (double)Wk[i];
}

// Fused: zero bmp/wl_cnt(+deg harmless) + q,k f64 (repair path) + bf16 hi/lo splits + h = nf@Wg.T.
// 1-D grid 1024, block 256, XCD-swizzled so batch b lives on XCD b/4 (matches k_score/k_gather:
// per-XCD working set 4 batches ~ 2 MiB < 4 MiB L2, and writes stay L2-resident for k_score).
__global__ __launch_bounds__(256) void k_prep(
    const float* __restrict__ x, const float* __restrict__ bq, const float* __restrict__ bk,
    const double* __restrict__ Wq64, const double* __restrict__ Wk64,
    const float* __restrict__ Wg,
    unsigned short* __restrict__ qh, unsigned short* __restrict__ ql,
    unsigned short* __restrict__ kh, unsigned short* __restrict__ kl,
    double* __restrict__ qT64, double* __restrict__ kT64,
    float* __restrict__ h,
    uint4* __restrict__ zbase, int zn)
{
    __shared__ float xs[64 * 129];   // xs[node][f], pad 129 -> conflict-free
    const int t = threadIdx.x;
    const int l = t & 63;
    const int w = t >> 6;
    const int uw = __builtin_amdgcn_readfirstlane(w);
    // XCD swizzle: lid contiguous per XCD (XCD = bid%8 round-robin assumption, T1)
    const int bid = blockIdx.x;                       // 0..1023
    const int lid = (bid & 7) * 128 + (bid >> 3);     // bijective
    const int b    = lid >> 5;                        // batch: 4 per XCD
    const int half = (lid >> 4) & 1;
    const int n0   = (lid & 15) * 64;

    // --- zero phase (deg + bmp + wl_cnt), grid-stride over 1024 blocks ---
    {
        int lid0 = bid * 256 + t;   // 0..262143
        for (int i = lid0; i < zn; i += 262144)
            zbase[i] = make_uint4(0u, 0u, 0u, 0u);
    }

    {   // xs[node][f] = x[b][f][n0+node]  (coalesced over node)
        const int j = t & 63, fg = t >> 6;
        for (int ff = 0; ff < 32; ++ff) {
            int f = fg + ff * 4;
            xs[j * 129 + f] = x[((size_t)b * NF + f) * NN + n0 + j];
        }
    }
    __syncthreads();

    // --- q/k phase (f64, 8 d-dims per wave) ---
    {
        const int d0 = half * 32 + uw * 8;
        double accq[8], acck[8];
        #pragma unroll
        for (int dd = 0; dd < 8; ++dd) {
            accq[dd] = (double)bq[d0 + dd];
            acck[dd] = (double)bk[d0 + dd];
        }
        for (int fc = 0; fc < 32; ++fc) {
            double dx0 = (double)xs[l * 129 + fc * 4 + 0];
            double dx1 = (double)xs[l * 129 + fc * 4 + 1];
            double dx2 = (double)xs[l * 129 + fc * 4 + 2];
            double dx3 = (double)xs[l * 129 + fc * 4 + 3];
            #pragma unroll
            for (int dd = 0; dd < 8; ++dd) {
                int d = d0 + dd;   // uniform -> scalar loads of weights
                const double* wq = &Wq64[d * NF + fc * 4];
                const double* wk = &Wk64[d * NF + fc * 4];
                accq[dd] += dx0 * wq[0] + dx1 * wq[1] + dx2 * wq[2] + dx3 * wq[3];
                acck[dd] += dx0 * wk[0] + dx1 * wk[1] + dx2 * wk[2] + dx3 * wk[3];
            }
        }
        // f64 [d][n] for repair (coalesced over lane)
        #pragma unroll
        for (int dd = 0; dd < 8; ++dd) {
            size_t idx = ((size_t)b * NDG + d0 + dd) * NN + n0 + l;
            qT64[idx] = accq[dd];
            kT64[idx] = acck[dd];
        }
        // bf16 hi/lo splits, [n][d] layout
        us8v qh0, ql0, kh0, kl0;
        #pragma unroll
        for (int dd = 0; dd < 8; ++dd) {
            float fq = (float)accq[dd];
            unsigned short h1 = bf16_rne(fq);
            unsigned short l1 = bf16_rne(fq - bf16_tof(h1));
            float fk = (float)acck[dd];
            unsigned short h2 = bf16_rne(fk);
            unsigned short l2 = bf16_rne(fk - bf16_tof(h2));
            qh0[dd] = h1; ql0[dd] = l1; kh0[dd] = h2; kl0[dd] = l2;
        }
        size_t nb = ((size_t)b * NN + n0 + l) * NDG + d0;
        *(us8v*)&qh[nb] = qh0;
        *(us8v*)&ql[nb] = ql0;
        *(us8v*)&kh[nb] = kh0;
        *(us8v*)&kl[nb] = kl0;
    }

    // --- h phase (f32, 16 out-features per wave; this block covers f' in [half*64, half*64+64)) ---
    {
        const int fp0 = half * 64 + uw * 16;
        float acc[16];
        #pragma unroll
        for (int i = 0; i < 16; ++i) acc[i] = 0.f;
        for (int fc = 0; fc < 32; ++fc) {
            float x0 = xs[l * 129 + fc * 4 + 0];
            float x1 = xs[l * 129 + fc * 4 + 1];
            float x2 = xs[l * 129 + fc * 4 + 2];
            float x3 = xs[l * 129 + fc * 4 + 3];
            #pragma unroll
            for (int ff = 0; ff < 16; ++ff) {
                const float* wg = &Wg[(fp0 + ff) * NF + fc * 4];
                acc[ff] += x0 * wg[0] + x1 * wg[1] + x2 * wg[2] + x3 * wg[3];
            }
        }
        __syncthreads();   // everyone done reading xs
        #pragma unroll
        for (int ff = 0; ff < 16; ++ff) xs[l * 129 + fp0 + ff] = acc[ff];
        __syncthreads();
        // write h[n][half*64 .. half*64+64) for the 64 nodes
        for (int r = 0; r < 16; ++r) {
            int idx = t + 256 * r;            // 0..4095
            int n = idx >> 6, f = idx & 63;
            h[((size_t)b * NN + n0 + n) * NF + half * 64 + f] = xs[n * 129 + half * 64 + f];
        }
    }
}

// two independent bitonic sort64 chains interleaved (latency overlap); descending, lane l = rank l
__device__ inline void bsort64_2(unsigned& va, unsigned& vb, int l) {
    #pragma unroll
    for (int k = 2; k <= 64; k <<= 1) {
        #pragma unroll
        for (int j = k >> 1; j >= 1; j >>= 1) {
            unsigned pa = (unsigned)__shfl_xor((int)va, j, 64);
            unsigned pb = (unsigned)__shfl_xor((int)vb, j, 64);
            bool tm = ((l & k) == 0) == ((l & j) == 0);
            unsigned ha = va > pa ? va : pa, la = va > pa ? pa : va;
            unsigned hb = vb > pb ? vb : pb, lb = vb > pb ? pb : vb;
            va = tm ? ha : la;
            vb = tm ? hb : lb;
        }
    }
}

// MFMA bf16-split scores, 32 rows/block, all-resident grid, XCD-swizzled:
// 1-D grid 1024; lid = (bid&7)*128 + bid>>3 puts batch b's 32 row-tile blocks on XCD b/4.
// Per-XCD K working set = 4 batches x 512 KB = 2 MiB < 4 MiB L2 -> K loads L2-hit (was L3 thrash).
// Statistical prefilter t_r = mean_r + 1.8*std_r; survivors ballot-compacted to slots[row][wave][24].
// Guard raw<16 | raw>64 | cell>24 -> dummy set + flagged -> exact f64 k_repair fixes the row.
// deg = popcount(bmp row) in k_deg after repair.
__global__ __launch_bounds__(256) void k_score(
    const unsigned short* __restrict__ qh, const unsigned short* __restrict__ ql,
    const unsigned short* __restrict__ kh, const unsigned short* __restrict__ kl,
    const float* __restrict__ bk,
    unsigned int* __restrict__ bmp,
    int* __restrict__ topk, int* __restrict__ wl_cnt, int* __restrict__ wl)
{
    __shared__ unsigned slots[32 * 96];   // [row][wave][24], 12 KiB
    __shared__ int      cntw[32 * 4];     // per-(row,wave) survivor count
    const int t = threadIdx.x, l = t & 63, w = t >> 6;   // w in [0,4)
    // XCD swizzle (T1): batch b -> XCD b/4, all 32 row-tiles of a batch co-located
    const int bid = blockIdx.x;                      // 0..1023
    const int lid = (bid & 7) * 128 + (bid >> 3);    // bijective
    const int b = lid >> 5, row0 = (lid & 31) * 32;
    const int m = l & 15, q4 = l >> 4;

    // A fragments: 2 row-groups of 16. A[m][k]: m=lane&15, k=(lane>>4)*8+j
    s8v ah0[2], ah1[2], al0[2], al1[2];
    #pragma unroll
    for (int g = 0; g < 2; ++g) {
        size_t abase = ((size_t)b * NN + row0 + g * 16 + m) * NDG + q4 * 8;
        ah0[g] = *(const s8v*)&qh[abase];
        ah1[g] = *(const s8v*)&qh[abase + 32];
        al0[g] = *(const s8v*)&ql[abase];
        al1[g] = *(const s8v*)&ql[abase + 32];
    }

    // per-row thresholds from q stats: scores ~ N(q.bk/8, |q|^2/64); t = mean + 1.8*std
    unsigned Trow[2][4];
    #pragma unroll
    for (int g = 0; g < 2; ++g) {
        float ssq = 0.f, smn = 0.f;
        #pragma unroll
        for (int j = 0; j < 8; ++j) {
            float q0 = bf16_tof(((us8v)ah0[g])[j]) + bf16_tof(((us8v)al0[g])[j]);
            float q1 = bf16_tof(((us8v)ah1[g])[j]) + bf16_tof(((us8v)al1[g])[j]);
            float b0 = bk[q4 * 8 + j];
            float b1 = bk[q4 * 8 + 32 + j];
            ssq += q0 * q0 + q1 * q1;
            smn += q0 * b0 + q1 * b1;
        }
        ssq += __shfl_xor(ssq, 16, 64); ssq += __shfl_xor(ssq, 32, 64);
        smn += __shfl_xor(smn, 16, 64); smn += __shfl_xor(smn, 32, 64);
        float t_m = 0.125f * smn + 0.2250f * __builtin_sqrtf(ssq);   // 1.8/8 = 0.225
        unsigned Tm = pack22(t_m) << 10;
        #pragma unroll
        for (int r = 0; r < 4; ++r)
            Trow[g][r] = (unsigned)__shfl((int)Tm, 4 * q4 + r, 64);
    }

    const int colbase = w * 256;
    int basec[2][4] = {{0,0,0,0},{0,0,0,0}};

    // B double-buffer: prefetch tt+1 while computing tt (static indices after full unroll)
    s8v Bh0[2], Bh1[2], Bl0[2], Bl1[2];
    {
        size_t bb = ((size_t)b * NN + colbase + m) * NDG + q4 * 8;
        Bh0[0] = *(const s8v*)&kh[bb];
        Bh1[0] = *(const s8v*)&kh[bb + 32];
        Bl0[0] = *(const s8v*)&kl[bb];
        Bl1[0] = *(const s8v*)&kl[bb + 32];
    }
    #pragma unroll
    for (int tt = 0; tt < 16; ++tt) {
        const int cur = tt & 1;
        if (tt < 15) {
            size_t bb = ((size_t)b * NN + colbase + (tt + 1) * 16 + m) * NDG + q4 * 8;
            Bh0[cur ^ 1] = *(const s8v*)&kh[bb];
            Bh1[cur ^ 1] = *(const s8v*)&kh[bb + 32];
            Bl0[cur ^ 1] = *(const s8v*)&kl[bb];
            Bl1[cur ^ 1] = *(const s8v*)&kl[bb + 32];
        }
        const int col = colbase + tt * 16 + m;
        #pragma unroll
        for (int g = 0; g < 2; ++g) {
            f4v acc = {0.f, 0.f, 0.f, 0.f};
            acc = __builtin_amdgcn_mfma_f32_16x16x32_bf16(al0[g], Bl0[cur], acc, 0, 0, 0);
            acc = __builtin_amdgcn_mfma_f32_16x16x32_bf16(al1[g], Bl1[cur], acc, 0, 0, 0);
            acc = __builtin_amdgcn_mfma_f32_16x16x32_bf16(ah0[g], Bl0[cur], acc, 0, 0, 0);
            acc = __builtin_amdgcn_mfma_f32_16x16x32_bf16(ah1[g], Bl1[cur], acc, 0, 0, 0);
            acc = __builtin_amdgcn_mfma_f32_16x16x32_bf16(al0[g], Bh0[cur], acc, 0, 0, 0);
            acc = __builtin_amdgcn_mfma_f32_16x16x32_bf16(al1[g], Bh1[cur], acc, 0, 0, 0);
            acc = __builtin_amdgcn_mfma_f32_16x16x32_bf16(ah0[g], Bh0[cur], acc, 0, 0, 0);
            acc = __builtin_amdgcn_mfma_f32_16x16x32_bf16(ah1[g], Bh1[cur], acc, 0, 0, 0);
            // C/D: col=lane&15, row=(lane>>4)*4+reg. Ballot-compact survivors per (row, wave).
            #pragma unroll
            for (int r = 0; r < 4; ++r) {
                const int rloc = g * 16 + q4 * 4 + r;      // local row 0..31
                const int grow = row0 + rloc;
                float s = acc[r] * 0.125f;
                unsigned c22 = (col == grow) ? 0u : pack22(s);
                unsigned v = (c22 << 10) | (unsigned)(1023 - col);
                bool p = v >= Trow[g][r];
                unsigned long long mk = __ballot(p);
                unsigned w16 = (unsigned)(mk >> (q4 * 16)) & 0xFFFFu;
                int idx = basec[g][r] + __popc(w16 & ((1u << m) - 1u));
                if (p && idx < 24) slots[rloc * 96 + w * 24 + idx] = v;
                basec[g][r] += __popc(w16);
            }
        }
    }
    // per-(row,wave) raw counts (overflow detectable: >24)
    if (m == 0) {
        #pragma unroll
        for (int g = 0; g < 2; ++g)
            #pragma unroll
            for (int r = 0; r < 4; ++r)
                cntw[(g * 16 + q4 * 4 + r) * 4 + w] = basec[g][r];
    }
    __syncthreads();

    // wave w merges rows [8w, 8w+8) as 4 pairs
    #pragma unroll
    for (int pp = 0; pp < 4; ++pp) {
        const int rA = w * 8 + 2 * pp, rB = rA + 1;
        int a0 = cntw[rA * 4 + 0], a1 = cntw[rA * 4 + 1], a2 = cntw[rA * 4 + 2], a3 = cntw[rA * 4 + 3];
        int b0 = cntw[rB * 4 + 0], b1 = cntw[rB * 4 + 1], b2 = cntw[rB * 4 + 2], b3 = cntw[rB * 4 + 3];
        bool ovA = (a0 > 24) || (a1 > 24) || (a2 > 24) || (a3 > 24);
        bool ovB = (b0 > 24) || (b1 > 24) || (b2 > 24) || (b3 > 24);
        int rawA = a0 + a1 + a2 + a3, rawB = b0 + b1 + b2 + b3;
        a0 = a0 > 24 ? 24 : a0; a1 = a1 > 24 ? 24 : a1; a2 = a2 > 24 ? 24 : a2; a3 = a3 > 24 ? 24 : a3;
        b0 = b0 > 24 ? 24 : b0; b1 = b1 > 24 ? 24 : b1; b2 = b2 > 24 ? 24 : b2; b3 = b3 > 24 ? 24 : b3;
        int PA1 = a0, PA2 = a0 + a1, PA3 = a0 + a1 + a2, CA = PA3 + a3;
        int PB1 = b0, PB2 = b0 + b1, PB3 = b0 + b1 + b2, CB = PB3 + b3;
        bool fbA = ovA || rawA < 16 || rawA > 64;
        bool fbB = ovB || rawB < 16 || rawB > 64;

        int jA = (l >= PA1) + (l >= PA2) + (l >= PA3);
        int jB = (l >= PB1) + (l >= PB2) + (l >= PB3);
        int baseA = jA == 0 ? 0 : (jA == 1 ? PA1 : (jA == 2 ? PA2 : PA3));
        int baseB = jB == 0 ? 0 : (jB == 1 ? PB1 : (jB == 2 ? PB2 : PB3));
        unsigned cva = (l < CA) ? slots[rA * 96 + jA * 24 + (l - baseA)] : 0u;
        unsigned cvb = (l < CB) ? slots[rB * 96 + jB * 24 + (l - baseB)] : 0u;
        bsort64_2(cva, cvb, l);   // lane l = rank-l value (descending)

        #pragma unroll
        for (int rr = 0; rr < 2; ++rr) {
            const int grow = row0 + (rr == 0 ? rA : rB);
            unsigned res   = rr == 0 ? cva : cvb;
            const bool fb  = rr == 0 ? fbA : fbB;

            unsigned r14 = (unsigned)__shfl((int)res, 14, 64);
            unsigned r15 = (unsigned)__shfl((int)res, 15, 64);
            bool flagged;
            if (fb) {
                flagged = true;
            } else {
                float s15 = dec22(r14 >> 10), s16 = dec22(r15 >> 10);
                unsigned e15 = (__float_as_uint(fabsf(s15)) >> 23) & 255u;
                unsigned e16 = (__float_as_uint(fabsf(s16)) >> 23) & 255u;
                unsigned e = e15 > e16 ? e15 : e16;
                float qq = __uint_as_float((e - 17) << 23);    // 22-bit code quantum
                flagged = (s15 - s16) < (4.f * qq + 1e-4f);
            }
            if (l < 15) {
                int col = fb ? ((grow + 1 + l) & 1023)          // dummy distinct non-self set
                             : (1023 - (int)(res & 1023u));
                atomicOr(&bmp[((size_t)b * NN + col) * 32 + (grow >> 5)], 1u << (grow & 31));
                if (flagged) topk[(b * NN + grow) * 16 + l] = col;
            }
            if (l == 0 && flagged) {
                int idx = atomicAdd(wl_cnt, 1);
                if (idx < 32767) wl[idx] = b * NN + grow;
            }
        }
    }
}

// exact f64 re-selection for worklist rows; patches bitmap by set-diff (deg derived later).
// grid 1024, block 256 (4 waves per ROW, cooperative): wave w handles cols [256w, 256w+256),
// 4 score chains per lane (scalars -> registers, no spill), scalar double-buffer over d.
// Selection: 15 block-wide argmax iterations (wave shfl-reduce -> 4 LDS candidates -> pick).
__global__ __launch_bounds__(256) void k_repair(
    const double* __restrict__ qT64, const double* __restrict__ kT64,
    const int* __restrict__ topk, const int* __restrict__ wl_cnt, const int* __restrict__ wl,
    unsigned int* __restrict__ bmp)
{
    const int t = threadIdx.x, l = t & 63, w = t >> 6;
    __shared__ double qld[64];
    __shared__ double cmax[4];
    __shared__ int    cidx[4];
    __shared__ int    oldset[15], newset[15];
    const double NEGINF = -__builtin_inf();
    int n = wl_cnt[0]; if (n > 32767) n = 32767;

    for (int i = blockIdx.x; i < n; i += 1024) {
        int rg = wl[i];
        int b = rg >> 10, row = rg & 1023;

        __syncthreads();   // guard qld/newset reuse across grid-stride iterations
        if (t < 64) qld[t] = qT64[((size_t)b * NDG + t) * NN + row];
        if (t < 15) oldset[t] = topk[(b * NN + row) * 16 + t];
        __syncthreads();

        const double* kb = &kT64[(size_t)b * NDG * NN];
        const int base = l + 256 * w;
        const int c0 = base, c1 = base + 64, c2 = base + 128, c3 = base + 192;
        double s0 = 0.0, s1 = 0.0, s2 = 0.0, s3 = 0.0;
        double b0 = kb[c0], b1 = kb[c1], b2 = kb[c2], b3 = kb[c3];
        for (int d = 0; d < 64; ++d) {
            double n0, n1, n2, n3;
            if (d < 63) {
                const double* kr = kb + (size_t)(d + 1) * NN;
                n0 = kr[c0]; n1 = kr[c1]; n2 = kr[c2]; n3 = kr[c3];
            }
            double qd = qld[d];
            s0 += qd * b0; s1 += qd * b1; s2 += qd * b2; s3 += qd * b3;
            if (d < 63) { b0 = n0; b1 = n1; b2 = n2; b3 = n3; }
        }
        if (c0 == row) s0 = NEGINF;
        if (c1 == row) s1 = NEGINF;
        if (c2 == row) s2 = NEGINF;
        if (c3 == row) s3 = NEGINF;

        for (int it = 0; it < 15; ++it) {
            double lv = NEGINF; int lc = 0x7fffffff;
            if (s0 > lv) { lv = s0; lc = c0; }
            if (s1 > lv) { lv = s1; lc = c1; }
            if (s2 > lv) { lv = s2; lc = c2; }
            if (s3 > lv) { lv = s3; lc = c3; }
            #pragma unroll
            for (int off = 1; off < 64; off <<= 1) {
                double ov = __shfl_xor(lv, off, 64);
                int    oc = __shfl_xor(lc, off, 64);
                if (ov > lv || (ov == lv && oc < lc)) { lv = ov; lc = oc; }
            }
            if (l == 0) { cmax[w] = lv; cidx[w] = lc; }
            __syncthreads();
            if (t == 0) {
                double bv = cmax[0]; int bc = cidx[0];
                #pragma unroll
                for (int ww = 1; ww < 4; ++ww)
                    if (cmax[ww] > bv || (cmax[ww] == bv && cidx[ww] < bc)) { bv = cmax[ww]; bc = cidx[ww]; }
                newset[it] = bc;
            }
            __syncthreads();
            int bc = newset[it];
            if (c0 == bc) s0 = NEGINF;
            if (c1 == bc) s1 = NEGINF;
            if (c2 == bc) s2 = NEGINF;
            if (c3 == bc) s3 = NEGINF;
        }

        if (t < 15) {
            int cn = newset[t];
            bool found = false;
            #pragma unroll
            for (int j = 0; j < 15; ++j) found = found || (oldset[j] == cn);
            if (!found)
                atomicOr(&bmp[((size_t)b * NN + cn) * 32 + (row >> 5)], 1u << (row & 31));
            int co = oldset[t];
            found = false;
            #pragma unroll
            for (int j = 0; j < 15; ++j) found = found || (newset[j] == co);
            if (!found)
                atomicAnd(&bmp[((size_t)b * NN + co) * 32 + (row >> 5)], ~(1u << (row & 31)));
        }
    }
}

// deg[b][n] = popcount of bmp row (number of rows that selected node n). grid 128, block 256.
__global__ __launch_bounds__(256) void k_deg(const unsigned int* __restrict__ bmp,
                                             int* __restrict__ deg)
{
    int i = blockIdx.x * 256 + threadIdx.x;   // 0..32767 over (b,n)
    const uint4* p = (const uint4*)(bmp + (size_t)i * 32);
    int s = 0;
    #pragma unroll
    for (int j = 0; j < 8; ++j) {
        uint4 v = p[j];
        s += __popc(v.x) + __popc(v.y) + __popc(v.z) + __popc(v.w);
    }
    deg[i] = s;
}

// gather per target via compacted LDS edge list + LDS norm table (dinv folded here).
// 1-D grid 32768, block 128 (f = thread), XCD-swizzled: batch b on XCD b/4 (h working set
// 4 x 512 KB = 2 MiB per XCD < L2). Edge loop 4-way unrolled for load ILP.
__global__ __launch_bounds__(128) void k_gather(
    const float* __restrict__ h, const float* __restrict__ bg,
    const int* __restrict__ deg, const unsigned int* __restrict__ bmp,
    float* __restrict__ tmp)
{
    __shared__ int list[1024];
    __shared__ float nrm[1024];
    __shared__ int scnt;
    const int bid = blockIdx.x;                        // 0..32767
    const int lid = (bid & 7) * 4096 + (bid >> 3);     // bijective, XCD chunks
    const int b = lid >> 10, tgt = lid & 1023;
    const int t = threadIdx.x;
    if (t < 32) {
        unsigned word = bmp[((size_t)b * NN + tgt) * 32 + t];
        int pc = __popc(word);
        int pre = pc;
        #pragma unroll
        for (int d = 1; d < 32; d <<= 1) {
            int o = __shfl_up(pre, d, 32);
            if (t >= d) pre += o;
        }
        if (t == 31) scnt = pre;
        int idx = pre - pc;
        while (word) {
            int s = __ffs(word) - 1;
            word &= word - 1;
            list[idx++] = t * 32 + s;
        }
    }
    __syncthreads();
    const int cnt = scnt;
    for (int e = t; e < cnt; e += 128)
        nrm[e] = rsqrtf((float)(deg[b * NN + list[e]] + 2));
    __syncthreads();
    const int f = t;
    float dt = rsqrtf((float)(deg[b * NN + tgt] + 2));
    float a0 = 0.f, a1 = 0.f, a2 = 0.f, a3 = 0.f;
    int e = 0;
    for (; e + 4 <= cnt; e += 4) {
        a0 += h[((size_t)b * NN + list[e + 0]) * NF + f] * nrm[e + 0];
        a1 += h[((size_t)b * NN + list[e + 1]) * NF + f] * nrm[e + 1];
        a2 += h[((size_t)b * NN + list[e + 2]) * NF + f] * nrm[e + 2];
        a3 += h[((size_t)b * NN + list[e + 3]) * NF + f] * nrm[e + 3];
    }
    for (; e < cnt; ++e)
        a0 += h[((size_t)b * NN + list[e]) * NF + f] * nrm[e];
    float acc = 2.0f * dt * h[((size_t)b * NN + tgt) * NF + f] + ((a0 + a1) + (a2 + a3));
    tmp[((size_t)b * NN + tgt) * NF + f] = bg[f] + dt * acc;
}

// [b][n][f] -> [b][f][n]. grid (32, 4, 32), block 256.
__global__ __launch_bounds__(256) void k_transpose(const float* __restrict__ tmp,
                                                   float* __restrict__ out)
{
    __shared__ float tile[32][33];
    const int t = threadIdx.x;
    const int n0 = blockIdx.x * 32, f0 = blockIdx.y * 32, b = blockIdx.z;
    const int c = t & 31, rb = t >> 5;
    #pragma unroll
    for (int i = 0; i < 4; ++i) {
        int r = rb + i * 8;
        tile[r][c] = tmp[((size_t)b * NN + n0 + r) * NF + f0 + c];
    }
    __syncthreads();
    #pragma unroll
    for (int i = 0; i < 4; ++i) {
        int r = rb + i * 8;
        out[((size_t)b * NF + f0 + r) * NN + n0 + c] = tile[c][r];
    }
}

extern "C" void kernel_launch(void* const* d_in, const int* in_sizes, int n_in,
                              void* d_out, int out_size, void* d_ws, size_t ws_size,
                              hipStream_t stream)
{
    const float* x  = (const float*)d_in[0];
    const float* Wq = (const float*)d_in[1];
    const float* bq = (const float*)d_in[2];
    const float* Wk = (const float*)d_in[3];
    const float* bk = (const float*)d_in[4];
    const float* Wg = (const float*)d_in[5];
    const float* bg = (const float*)d_in[6];
    float* out = (float*)d_out;
    char* ws = (char*)d_ws;

    unsigned short* qh = (unsigned short*)(ws + OFF_QH);
    unsigned short* ql = (unsigned short*)(ws + OFF_QL);
    unsigned short* kh = (unsigned short*)(ws + OFF_KH);
    unsigned short* kl = (unsigned short*)(ws + OFF_KL);
    float*          h   = (float*)(ws + OFF_H);
    int*            deg = (int*)(ws + OFF_DEG);
    unsigned int*   bmp = (unsigned int*)(ws + OFF_BMP);
    int*            wlc = (int*)(ws + OFF_WL);
    int*            wl  = wlc + 1;
    int*            tpk = (int*)(ws + OFF_TOPK);
    double*         Wq64 = (double*)(ws + OFF_W64);
    double*         Wk64 = Wq64 + 8192;
    double*         qT64 = (double*)(ws + OFF_QT64);
    double*         kT64 = (double*)(ws + OFF_KT64);
    float*          tmp  = (float*)(ws + OFF_TMP);

    k_upcast<<<32, 256, 0, stream>>>(Wq, Wk, Wq64, Wk64);
    // zero range: deg + bmp + wl_cnt = 4,325,392 B = 270337 uint4 (done inside k_prep)
    k_prep<<<1024, 256, 0, stream>>>(x, bq, bk, Wq64, Wk64, Wg,
                                     qh, ql, kh, kl, qT64, kT64, h,
                                     (uint4*)(ws + OFF_DEG), 270337);
    k_score<<<1024, 256, 0, stream>>>(qh, ql, kh, kl, bk, bmp, tpk, wlc, wl);
    k_repair<<<1024, 256, 0, stream>>>(qT64, kT64, tpk, wlc, wl, bmp);
    k_deg<<<128, 256, 0, stream>>>(bmp, deg);
    k_gather<<<32768, 128, 0, stream>>>(h, bg, deg, bmp, tmp);
    k_transpose<<<dim3(32, 4, 32), 256, 0, stream>>>(tmp, out);
}

// Round 8
// 257.521 us; speedup vs baseline: 1.4747x; 1.0543x over previous
//
#include <hip/hip_runtime.h>

#define NBATCH 32
#define NN     1024     // d_model = number of nodes
#define NF     128      // win_size = node feature dim
#define NDG    64       // graph embed dim
#define TOPK   15

// ---------------- workspace layout (bytes) ----------------
#define OFF_QH    ((size_t)0)            // bf16-hi q [32][1024][64]  4 MiB
#define OFF_QL    ((size_t)4194304)      // bf16-lo q                 4 MiB
#define OFF_KH    ((size_t)8388608)      // bf16-hi k                 4 MiB
#define OFF_KL    ((size_t)12582912)     // bf16-lo k                 4 MiB
#define OFF_H     ((size_t)16777216)     // f32 [32][1024][128]      16 MiB
#define OFF_DEG   ((size_t)33554432)     // i32 [32][1024]          128 KiB
#define OFF_BMP   ((size_t)33685504)     // u32 [32][1024][32]        4 MiB
#define OFF_WL    ((size_t)37879808)     // wl_cnt + wl[32767]      128 KiB
#define OFF_TOPK  ((size_t)38010880)     // i32 [32][1024][16]        2 MiB
#define OFF_KT32  ((size_t)40239104)     // f32 [32][64][1024]        8 MiB (k for repair)
#define OFF_TMP   ((size_t)0)            // f32 [32][1024][128]      16 MiB (overlaps QH..KL, dead by then)

typedef short s8v  __attribute__((ext_vector_type(8)));   // 8 bf16 (4 VGPRs) MFMA operand
typedef float f4v  __attribute__((ext_vector_type(4)));   // MFMA accumulator
typedef unsigned short us8v __attribute__((ext_vector_type(8)));

__device__ inline unsigned short bf16_rne(float f) {
    unsigned u = __float_as_uint(f);
    return (unsigned short)((u + 0x7FFFu + ((u >> 16) & 1u)) >> 16);
}
__device__ inline float bf16_tof(unsigned short h) { return __uint_as_float(((unsigned)h) << 16); }

// monotone 22-bit code for f32 score in window [-4, 4): sign + 5-bit biased exp + 16-bit mantissa
__device__ inline unsigned pack22(float s) {
    unsigned u   = __float_as_uint(s);
    int      mag = (int)(u & 0x7FFFFFFFu);
    int      t   = mag - 0x38800000;                 // bias at 2^-14
    t = t < 0 ? 0 : (t > 0x07FFFFFF ? 0x07FFFFFF : t);
    unsigned ts = (unsigned)t >> 6;                  // 21 bits
    return ((int)u < 0) ? (0x1FFFFFu - ts) : (0x200000u | ts);
}
__device__ inline float dec22(unsigned val22) {
    bool pos = (val22 & 0x200000u) != 0;
    unsigned ts = pos ? (val22 & 0x1FFFFFu) : (0x1FFFFFu - (val22 & 0x1FFFFFu));
    float f = __uint_as_float((ts << 6) + 0x38800000u);
    return pos ? f : -f;
}

// Fused: zero bmp/deg/wl_cnt + q,k f32 + bf16 hi/lo splits + kT32 (repair) + h = nf@Wg.T.
// 1-D grid 1024, block 256, XCD-swizzled so batch b lives on XCD b/4 (matches k_score/k_gather:
// per-XCD working set 4 batches ~ 2 MiB < 4 MiB L2, and writes stay L2-resident for k_score).
// All-f32 compute: f64 removed (was ~half the VALU cost at half rate); repair gets f32 k +
// on-the-fly f64 q (products exact in f64; selection error ~1e-7 rel, statistically safe).
__global__ __launch_bounds__(256) void k_prep(
    const float* __restrict__ x, const float* __restrict__ bq, const float* __restrict__ bk,
    const float* __restrict__ Wq, const float* __restrict__ Wk,
    const float* __restrict__ Wg,
    unsigned short* __restrict__ qh, unsigned short* __restrict__ ql,
    unsigned short* __restrict__ kh, unsigned short* __restrict__ kl,
    float* __restrict__ kT32,
    float* __restrict__ h,
    uint4* __restrict__ zbase, int zn)
{
    __shared__ float xs[64 * 129];   // xs[node][f], pad 129 -> conflict-free
    const int t = threadIdx.x;
    const int l = t & 63;
    const int w = t >> 6;
    const int uw = __builtin_amdgcn_readfirstlane(w);
    // XCD swizzle: lid contiguous per XCD (XCD = bid%8 round-robin assumption, T1)
    const int bid = blockIdx.x;                       // 0..1023
    const int lid = (bid & 7) * 128 + (bid >> 3);     // bijective
    const int b    = lid >> 5;                        // batch: 4 per XCD
    const int half = (lid >> 4) & 1;
    const int n0   = (lid & 15) * 64;

    // --- zero phase (deg + bmp + wl_cnt), grid-stride over 1024 blocks ---
    {
        int lid0 = bid * 256 + t;   // 0..262143
        for (int i = lid0; i < zn; i += 262144)
            zbase[i] = make_uint4(0u, 0u, 0u, 0u);
    }

    {   // xs[node][f] = x[b][f][n0+node]  (coalesced over node)
        const int j = t & 63, fg = t >> 6;
        for (int ff = 0; ff < 32; ++ff) {
            int f = fg + ff * 4;
            xs[j * 129 + f] = x[((size_t)b * NF + f) * NN + n0 + j];
        }
    }
    __syncthreads();

    // --- q/k phase (f32, 8 d-dims per wave) ---
    {
        const int d0 = half * 32 + uw * 8;
        float accq[8], acck[8];
        #pragma unroll
        for (int dd = 0; dd < 8; ++dd) {
            accq[dd] = bq[d0 + dd];
            acck[dd] = bk[d0 + dd];
        }
        for (int fc = 0; fc < 32; ++fc) {
            float x0 = xs[l * 129 + fc * 4 + 0];
            float x1 = xs[l * 129 + fc * 4 + 1];
            float x2 = xs[l * 129 + fc * 4 + 2];
            float x3 = xs[l * 129 + fc * 4 + 3];
            #pragma unroll
            for (int dd = 0; dd < 8; ++dd) {
                int d = d0 + dd;   // uniform -> scalar loads of weights
                const float* wq = &Wq[d * NF + fc * 4];
                const float* wk = &Wk[d * NF + fc * 4];
                accq[dd] += x0 * wq[0] + x1 * wq[1] + x2 * wq[2] + x3 * wq[3];
                acck[dd] += x0 * wk[0] + x1 * wk[1] + x2 * wk[2] + x3 * wk[3];
            }
        }
        // k f32 [d][n] for repair (coalesced over lane)
        #pragma unroll
        for (int dd = 0; dd < 8; ++dd)
            kT32[((size_t)b * NDG + d0 + dd) * NN + n0 + l] = acck[dd];
        // bf16 hi/lo splits, [n][d] layout
        us8v qh0, ql0, kh0, kl0;
        #pragma unroll
        for (int dd = 0; dd < 8; ++dd) {
            unsigned short h1 = bf16_rne(accq[dd]);
            unsigned short l1 = bf16_rne(accq[dd] - bf16_tof(h1));
            unsigned short h2 = bf16_rne(acck[dd]);
            unsigned short l2 = bf16_rne(acck[dd] - bf16_tof(h2));
            qh0[dd] = h1; ql0[dd] = l1; kh0[dd] = h2; kl0[dd] = l2;
        }
        size_t nb = ((size_t)b * NN + n0 + l) * NDG + d0;
        *(us8v*)&qh[nb] = qh0;
        *(us8v*)&ql[nb] = ql0;
        *(us8v*)&kh[nb] = kh0;
        *(us8v*)&kl[nb] = kl0;
    }

    // --- h phase (f32, 16 out-features per wave; this block covers f' in [half*64, half*64+64)) ---
    {
        const int fp0 = half * 64 + uw * 16;
        float acc[16];
        #pragma unroll
        for (int i = 0; i < 16; ++i) acc[i] = 0.f;
        for (int fc = 0; fc < 32; ++fc) {
            float x0 = xs[l * 129 + fc * 4 + 0];
            float x1 = xs[l * 129 + fc * 4 + 1];
            float x2 = xs[l * 129 + fc * 4 + 2];
            float x3 = xs[l * 129 + fc * 4 + 3];
            #pragma unroll
            for (int ff = 0; ff < 16; ++ff) {
                const float* wg = &Wg[(fp0 + ff) * NF + fc * 4];
                acc[ff] += x0 * wg[0] + x1 * wg[1] + x2 * wg[2] + x3 * wg[3];
            }
        }
        __syncthreads();   // everyone done reading xs
        #pragma unroll
        for (int ff = 0; ff < 16; ++ff) xs[l * 129 + fp0 + ff] = acc[ff];
        __syncthreads();
        // write h[n][half*64 .. half*64+64) for the 64 nodes
        for (int r = 0; r < 16; ++r) {
            int idx = t + 256 * r;            // 0..4095
            int n = idx >> 6, f = idx & 63;
            h[((size_t)b * NN + n0 + n) * NF + half * 64 + f] = xs[n * 129 + half * 64 + f];
        }
    }
}

// two independent bitonic sort64 chains interleaved (latency overlap); descending, lane l = rank l
__device__ inline void bsort64_2(unsigned& va, unsigned& vb, int l) {
    #pragma unroll
    for (int k = 2; k <= 64; k <<= 1) {
        #pragma unroll
        for (int j = k >> 1; j >= 1; j >>= 1) {
            unsigned pa = (unsigned)__shfl_xor((int)va, j, 64);
            unsigned pb = (unsigned)__shfl_xor((int)vb, j, 64);
            bool tm = ((l & k) == 0) == ((l & j) == 0);
            unsigned ha = va > pa ? va : pa, la = va > pa ? pa : va;
            unsigned hb = vb > pb ? vb : pb, lb = vb > pb ? pb : vb;
            va = tm ? ha : la;
            vb = tm ? hb : lb;
        }
    }
}

// MFMA bf16-split scores, 32 rows/block, all-resident grid, XCD-swizzled (T1).
// Prefilter now compares raw f32 acc against 8*t_m (1 cmp); pack22 runs only inside the
// survivor-predicated store (~4% of elements) -> ~6 VALU/element removed from the hot loop.
// Guard raw<16 | raw>64 | cell>24 -> dummy set + flagged -> exact k_repair fixes the row.
__global__ __launch_bounds__(256) void k_score(
    const unsigned short* __restrict__ qh, const unsigned short* __restrict__ ql,
    const unsigned short* __restrict__ kh, const unsigned short* __restrict__ kl,
    const float* __restrict__ bk,
    unsigned int* __restrict__ bmp,
    int* __restrict__ topk, int* __restrict__ wl_cnt, int* __restrict__ wl)
{
    __shared__ unsigned slots[32 * 96];   // [row][wave][24], 12 KiB
    __shared__ int      cntw[32 * 4];     // per-(row,wave) survivor count
    const int t = threadIdx.x, l = t & 63, w = t >> 6;   // w in [0,4)
    // XCD swizzle (T1): batch b -> XCD b/4, all 32 row-tiles of a batch co-located
    const int bid = blockIdx.x;                      // 0..1023
    const int lid = (bid & 7) * 128 + (bid >> 3);    // bijective
    const int b = lid >> 5, row0 = (lid & 31) * 32;
    const int m = l & 15, q4 = l >> 4;

    // A fragments: 2 row-groups of 16. A[m][k]: m=lane&15, k=(lane>>4)*8+j
    s8v ah0[2], ah1[2], al0[2], al1[2];
    #pragma unroll
    for (int g = 0; g < 2; ++g) {
        size_t abase = ((size_t)b * NN + row0 + g * 16 + m) * NDG + q4 * 8;
        ah0[g] = *(const s8v*)&qh[abase];
        ah1[g] = *(const s8v*)&qh[abase + 32];
        al0[g] = *(const s8v*)&ql[abase];
        al1[g] = *(const s8v*)&ql[abase + 32];
    }

    // per-row thresholds from q stats: scores ~ N(q.bk/8, |q|^2/64); t = mean + 1.8*std.
    // Tr holds 8*t_m so the filter compares raw MFMA acc (pre-0.125 scale) directly.
    float Tr[2][4];
    #pragma unroll
    for (int g = 0; g < 2; ++g) {
        float ssq = 0.f, smn = 0.f;
        #pragma unroll
        for (int j = 0; j < 8; ++j) {
            float q0 = bf16_tof(((us8v)ah0[g])[j]) + bf16_tof(((us8v)al0[g])[j]);
            float q1 = bf16_tof(((us8v)ah1[g])[j]) + bf16_tof(((us8v)al1[g])[j]);
            float b0 = bk[q4 * 8 + j];
            float b1 = bk[q4 * 8 + 32 + j];
            ssq += q0 * q0 + q1 * q1;
            smn += q0 * b0 + q1 * b1;
        }
        ssq += __shfl_xor(ssq, 16, 64); ssq += __shfl_xor(ssq, 32, 64);
        smn += __shfl_xor(smn, 16, 64); smn += __shfl_xor(smn, 32, 64);
        float t8 = smn + 1.8f * __builtin_sqrtf(ssq);   // 8 * (0.125*smn + 0.225*sqrt(ssq))
        #pragma unroll
        for (int r = 0; r < 4; ++r)
            Tr[g][r] = __shfl(t8, 4 * q4 + r, 64);
    }

    const int colbase = w * 256;
    int basec[2][4] = {{0,0,0,0},{0,0,0,0}};

    // B double-buffer: prefetch tt+1 while computing tt (static indices after full unroll)
    s8v Bh0[2], Bh1[2], Bl0[2], Bl1[2];
    {
        size_t bb = ((size_t)b * NN + colbase + m) * NDG + q4 * 8;
        Bh0[0] = *(const s8v*)&kh[bb];
        Bh1[0] = *(const s8v*)&kh[bb + 32];
        Bl0[0] = *(const s8v*)&kl[bb];
        Bl1[0] = *(const s8v*)&kl[bb + 32];
    }
    #pragma unroll
    for (int tt = 0; tt < 16; ++tt) {
        const int cur = tt & 1;
        if (tt < 15) {
            size_t bb = ((size_t)b * NN + colbase + (tt + 1) * 16 + m) * NDG + q4 * 8;
            Bh0[cur ^ 1] = *(const s8v*)&kh[bb];
            Bh1[cur ^ 1] = *(const s8v*)&kh[bb + 32];
            Bl0[cur ^ 1] = *(const s8v*)&kl[bb];
            Bl1[cur ^ 1] = *(const s8v*)&kl[bb + 32];
        }
        const int col = colbase + tt * 16 + m;
        #pragma unroll
        for (int g = 0; g < 2; ++g) {
            f4v acc = {0.f, 0.f, 0.f, 0.f};
            acc = __builtin_amdgcn_mfma_f32_16x16x32_bf16(al0[g], Bl0[cur], acc, 0, 0, 0);
            acc = __builtin_amdgcn_mfma_f32_16x16x32_bf16(al1[g], Bl1[cur], acc, 0, 0, 0);
            acc = __builtin_amdgcn_mfma_f32_16x16x32_bf16(ah0[g], Bl0[cur], acc, 0, 0, 0);
            acc = __builtin_amdgcn_mfma_f32_16x16x32_bf16(ah1[g], Bl1[cur], acc, 0, 0, 0);
            acc = __builtin_amdgcn_mfma_f32_16x16x32_bf16(al0[g], Bh0[cur], acc, 0, 0, 0);
            acc = __builtin_amdgcn_mfma_f32_16x16x32_bf16(al1[g], Bh1[cur], acc, 0, 0, 0);
            acc = __builtin_amdgcn_mfma_f32_16x16x32_bf16(ah0[g], Bh0[cur], acc, 0, 0, 0);
            acc = __builtin_amdgcn_mfma_f32_16x16x32_bf16(ah1[g], Bh1[cur], acc, 0, 0, 0);
            // C/D: col=lane&15, row=(lane>>4)*4+reg. Ballot-compact survivors per (row, wave).
            #pragma unroll
            for (int r = 0; r < 4; ++r) {
                const int rloc = g * 16 + q4 * 4 + r;      // local row 0..31
                const int grow = row0 + rloc;
                bool p = (acc[r] >= Tr[g][r]) && (col != grow);
                unsigned long long mk = __ballot(p);
                unsigned w16 = (unsigned)(mk >> (q4 * 16)) & 0xFFFFu;
                int idx = basec[g][r] + __popc(w16 & ((1u << m) - 1u));
                if (p && idx < 24) {
                    float s = acc[r] * 0.125f;
                    slots[rloc * 96 + w * 24 + idx] = (pack22(s) << 10) | (unsigned)(1023 - col);
                }
                basec[g][r] += __popc(w16);
            }
        }
    }
    // per-(row,wave) raw counts (overflow detectable: >24)
    if (m == 0) {
        #pragma unroll
        for (int g = 0; g < 2; ++g)
            #pragma unroll
            for (int r = 0; r < 4; ++r)
                cntw[(g * 16 + q4 * 4 + r) * 4 + w] = basec[g][r];
    }
    __syncthreads();

    // wave w merges rows [8w, 8w+8) as 4 pairs
    #pragma unroll
    for (int pp = 0; pp < 4; ++pp) {
        const int rA = w * 8 + 2 * pp, rB = rA + 1;
        int a0 = cntw[rA * 4 + 0], a1 = cntw[rA * 4 + 1], a2 = cntw[rA * 4 + 2], a3 = cntw[rA * 4 + 3];
        int b0 = cntw[rB * 4 + 0], b1 = cntw[rB * 4 + 1], b2 = cntw[rB * 4 + 2], b3 = cntw[rB * 4 + 3];
        bool ovA = (a0 > 24) || (a1 > 24) || (a2 > 24) || (a3 > 24);
        bool ovB = (b0 > 24) || (b1 > 24) || (b2 > 24) || (b3 > 24);
        int rawA = a0 + a1 + a2 + a3, rawB = b0 + b1 + b2 + b3;
        a0 = a0 > 24 ? 24 : a0; a1 = a1 > 24 ? 24 : a1; a2 = a2 > 24 ? 24 : a2; a3 = a3 > 24 ? 24 : a3;
        b0 = b0 > 24 ? 24 : b0; b1 = b1 > 24 ? 24 : b1; b2 = b2 > 24 ? 24 : b2; b3 = b3 > 24 ? 24 : b3;
        int PA1 = a0, PA2 = a0 + a1, PA3 = a0 + a1 + a2, CA = PA3 + a3;
        int PB1 = b0, PB2 = b0 + b1, PB3 = b0 + b1 + b2, CB = PB3 + b3;
        bool fbA = ovA || rawA < 16 || rawA > 64;
        bool fbB = ovB || rawB < 16 || rawB > 64;

        int jA = (l >= PA1) + (l >= PA2) + (l >= PA3);
        int jB = (l >= PB1) + (l >= PB2) + (l >= PB3);
        int baseA = jA == 0 ? 0 : (jA == 1 ? PA1 : (jA == 2 ? PA2 : PA3));
        int baseB = jB == 0 ? 0 : (jB == 1 ? PB1 : (jB == 2 ? PB2 : PB3));
        unsigned cva = (l < CA) ? slots[rA * 96 + jA * 24 + (l - baseA)] : 0u;
        unsigned cvb = (l < CB) ? slots[rB * 96 + jB * 24 + (l - baseB)] : 0u;
        bsort64_2(cva, cvb, l);   // lane l = rank-l value (descending)

        #pragma unroll
        for (int rr = 0; rr < 2; ++rr) {
            const int grow = row0 + (rr == 0 ? rA : rB);
            unsigned res   = rr == 0 ? cva : cvb;
            const bool fb  = rr == 0 ? fbA : fbB;

            unsigned r14 = (unsigned)__shfl((int)res, 14, 64);
            unsigned r15 = (unsigned)__shfl((int)res, 15, 64);
            bool flagged;
            if (fb) {
                flagged = true;
            } else {
                float s15 = dec22(r14 >> 10), s16 = dec22(r15 >> 10);
                unsigned e15 = (__float_as_uint(fabsf(s15)) >> 23) & 255u;
                unsigned e16 = (__float_as_uint(fabsf(s16)) >> 23) & 255u;
                unsigned e = e15 > e16 ? e15 : e16;
                float qq = __uint_as_float((e - 17) << 23);    // 22-bit code quantum
                flagged = (s15 - s16) < (4.f * qq + 1e-4f);
            }
            if (l < 15) {
                int col = fb ? ((grow + 1 + l) & 1023)          // dummy distinct non-self set
                             : (1023 - (int)(res & 1023u));
                atomicOr(&bmp[((size_t)b * NN + col) * 32 + (grow >> 5)], 1u << (grow & 31));
                if (flagged) topk[(b * NN + grow) * 16 + l] = col;
            }
            if (l == 0 && flagged) {
                int idx = atomicAdd(wl_cnt, 1);
                if (idx < 32767) wl[idx] = b * NN + grow;
            }
        }
    }
}

// exact re-selection for worklist rows; patches bitmap by set-diff (deg derived later).
// grid 1024, block 256 (4 waves per ROW): q of the flagged row recomputed on the fly in f64
// from x + f32 Wq (products exact); scores = f64 accumulation over f32 k (kT32).
// Selection: 15 block-wide argmax iterations (wave shfl-reduce -> 4 LDS candidates -> pick).
__global__ __launch_bounds__(256) void k_repair(
    const float* __restrict__ x, const float* __restrict__ bq, const float* __restrict__ Wq,
    const float* __restrict__ kT32,
    const int* __restrict__ topk, const int* __restrict__ wl_cnt, const int* __restrict__ wl,
    unsigned int* __restrict__ bmp)
{
    const int t = threadIdx.x, l = t & 63, w = t >> 6;
    __shared__ float  xrow[128];
    __shared__ double qld[64];
    __shared__ double cmax[4];
    __shared__ int    cidx[4];
    __shared__ int    oldset[15], newset[15];
    const double NEGINF = -__builtin_inf();
    int n = wl_cnt[0]; if (n > 32767) n = 32767;

    for (int i = blockIdx.x; i < n; i += 1024) {
        int rg = wl[i];
        int b = rg >> 10, row = rg & 1023;

        __syncthreads();   // guard shared reuse across grid-stride iterations
        if (t < 128) xrow[t] = x[((size_t)b * NF + t) * NN + row];
        if (t < 15) oldset[t] = topk[(b * NN + row) * 16 + t];
        __syncthreads();
        if (t < 64) {   // q[d] for this row, f64 accumulation of f32 products
            double acc = (double)bq[t];
            const float* wq = &Wq[t * NF];
            for (int f = 0; f < 128; ++f)
                acc += (double)xrow[f] * (double)wq[f];
            qld[t] = acc;
        }
        __syncthreads();

        const float* kb = &kT32[(size_t)b * NDG * NN];
        const int base = l + 256 * w;
        const int c0 = base, c1 = base + 64, c2 = base + 128, c3 = base + 192;
        double s0 = 0.0, s1 = 0.0, s2 = 0.0, s3 = 0.0;
        float b0 = kb[c0], b1 = kb[c1], b2 = kb[c2], b3 = kb[c3];
        for (int d = 0; d < 64; ++d) {
            float n0, n1, n2, n3;
            if (d < 63) {
                const float* kr = kb + (size_t)(d + 1) * NN;
                n0 = kr[c0]; n1 = kr[c1]; n2 = kr[c2]; n3 = kr[c3];
            }
            double qd = qld[d];
            s0 += qd * (double)b0; s1 += qd * (double)b1;
            s2 += qd * (double)b2; s3 += qd * (double)b3;
            if (d < 63) { b0 = n0; b1 = n1; b2 = n2; b3 = n3; }
        }
        if (c0 == row) s0 = NEGINF;
        if (c1 == row) s1 = NEGINF;
        if (c2 == row) s2 = NEGINF;
        if (c3 == row) s3 = NEGINF;

        for (int it = 0; it < 15; ++it) {
            double lv = NEGINF; int lc = 0x7fffffff;
            if (s0 > lv) { lv = s0; lc = c0; }
            if (s1 > lv) { lv = s1; lc = c1; }
            if (s2 > lv) { lv = s2; lc = c2; }
            if (s3 > lv) { lv = s3; lc = c3; }
            #pragma unroll
            for (int off = 1; off < 64; off <<= 1) {
                double ov = __shfl_xor(lv, off, 64);
                int    oc = __shfl_xor(lc, off, 64);
                if (ov > lv || (ov == lv && oc < lc)) { lv = ov; lc = oc; }
            }
            if (l == 0) { cmax[w] = lv; cidx[w] = lc; }
            __syncthreads();
            if (t == 0) {
                double bv = cmax[0]; int bc = cidx[0];
                #pragma unroll
                for (int ww = 1; ww < 4; ++ww)
                    if (cmax[ww] > bv || (cmax[ww] == bv && cidx[ww] < bc)) { bv = cmax[ww]; bc = cidx[ww]; }
                newset[it] = bc;
            }
            __syncthreads();
            int bc = newset[it];
            if (c0 == bc) s0 = NEGINF;
            if (c1 == bc) s1 = NEGINF;
            if (c2 == bc) s2 = NEGINF;
            if (c3 == bc) s3 = NEGINF;
        }

        if (t < 15) {
            int cn = newset[t];
            bool found = false;
            #pragma unroll
            for (int j = 0; j < 15; ++j) found = found || (oldset[j] == cn);
            if (!found)
                atomicOr(&bmp[((size_t)b * NN + cn) * 32 + (row >> 5)], 1u << (row & 31));
            int co = oldset[t];
            found = false;
            #pragma unroll
            for (int j = 0; j < 15; ++j) found = found || (newset[j] == co);
            if (!found)
                atomicAnd(&bmp[((size_t)b * NN + co) * 32 + (row >> 5)], ~(1u << (row & 31)));
        }
    }
}

// deg[b][n] = popcount of bmp row (number of rows that selected node n). grid 128, block 256.
__global__ __launch_bounds__(256) void k_deg(const unsigned int* __restrict__ bmp,
                                             int* __restrict__ deg)
{
    int i = blockIdx.x * 256 + threadIdx.x;   // 0..32767 over (b,n)
    const uint4* p = (const uint4*)(bmp + (size_t)i * 32);
    int s = 0;
    #pragma unroll
    for (int j = 0; j < 8; ++j) {
        uint4 v = p[j];
        s += __popc(v.x) + __popc(v.y) + __popc(v.z) + __popc(v.w);
    }
    deg[i] = s;
}

// gather per target via compacted LDS edge list + LDS norm table (dinv folded here).
// 1-D grid 32768, block 128 (f = thread), XCD-swizzled: batch b on XCD b/4 (h working set
// 4 x 512 KB = 2 MiB per XCD < L2). Edge loop 4-way unrolled for load ILP.
__global__ __launch_bounds__(128) void k_gather(
    const float* __restrict__ h, const float* __restrict__ bg,
    const int* __restrict__ deg, const unsigned int* __restrict__ bmp,
    float* __restrict__ tmp)
{
    __shared__ int list[1024];
    __shared__ float nrm[1024];
    __shared__ int scnt;
    const int bid = blockIdx.x;                        // 0..32767
    const int lid = (bid & 7) * 4096 + (bid >> 3);     // bijective, XCD chunks
    const int b = lid >> 10, tgt = lid & 1023;
    const int t = threadIdx.x;
    if (t < 32) {
        unsigned word = bmp[((size_t)b * NN + tgt) * 32 + t];
        int pc = __popc(word);
        int pre = pc;
        #pragma unroll
        for (int d = 1; d < 32; d <<= 1) {
            int o = __shfl_up(pre, d, 32);
            if (t >= d) pre += o;
        }
        if (t == 31) scnt = pre;
        int idx = pre - pc;
        while (word) {
            int s = __ffs(word) - 1;
            word &= word - 1;
            list[idx++] = t * 32 + s;
        }
    }
    __syncthreads();
    const int cnt = scnt;
    for (int e = t; e < cnt; e += 128)
        nrm[e] = rsqrtf((float)(deg[b * NN + list[e]] + 2));
    __syncthreads();
    const int f = t;
    float dt = rsqrtf((float)(deg[b * NN + tgt] + 2));
    float a0 = 0.f, a1 = 0.f, a2 = 0.f, a3 = 0.f;
    int e = 0;
    for (; e + 4 <= cnt; e += 4) {
        a0 += h[((size_t)b * NN + list[e + 0]) * NF + f] * nrm[e + 0];
        a1 += h[((size_t)b * NN + list[e + 1]) * NF + f] * nrm[e + 1];
        a2 += h[((size_t)b * NN + list[e + 2]) * NF + f] * nrm[e + 2];
        a3 += h[((size_t)b * NN + list[e + 3]) * NF + f] * nrm[e + 3];
    }
    for (; e < cnt; ++e)
        a0 += h[((size_t)b * NN + list[e]) * NF + f] * nrm[e];
    float acc = 2.0f * dt * h[((size_t)b * NN + tgt) * NF + f] + ((a0 + a1) + (a2 + a3));
    tmp[((size_t)b * NN + tgt) * NF + f] = bg[f] + dt * acc;
}

// [b][n][f] -> [b][f][n]. grid (32, 4, 32), block 256.
__global__ __launch_bounds__(256) void k_transpose(const float* __restrict__ tmp,
                                                   float* __restrict__ out)
{
    __shared__ float tile[32][33];
    const int t = threadIdx.x;
    const int n0 = blockIdx.x * 32, f0 = blockIdx.y * 32, b = blockIdx.z;
    const int c = t & 31, rb = t >> 5;
    #pragma unroll
    for (int i = 0; i < 4; ++i) {
        int r = rb + i * 8;
        tile[r][c] = tmp[((size_t)b * NN + n0 + r) * NF + f0 + c];
    }
    __syncthreads();
    #pragma unroll
    for (int i = 0; i < 4; ++i) {
        int r = rb + i * 8;
        out[((size_t)b * NF + f0 + r) * NN + n0 + c] = tile[c][r];
    }
}

extern "C" void kernel_launch(void* const* d_in, const int* in_sizes, int n_in,
                              void* d_out, int out_size, void* d_ws, size_t ws_size,
                              hipStream_t stream)
{
    const float* x  = (const float*)d_in[0];
    const float* Wq = (const float*)d_in[1];
    const float* bq = (const float*)d_in[2];
    const float* Wk = (const float*)d_in[3];
    const float* bk = (const float*)d_in[4];
    const float* Wg = (const float*)d_in[5];
    const float* bg = (const float*)d_in[6];
    float* out = (float*)d_out;
    char* ws = (char*)d_ws;

    unsigned short* qh = (unsigned short*)(ws + OFF_QH);
    unsigned short* ql = (unsigned short*)(ws + OFF_QL);
    unsigned short* kh = (unsigned short*)(ws + OFF_KH);
    unsigned short* kl = (unsigned short*)(ws + OFF_KL);
    float*          h   = (float*)(ws + OFF_H);
    int*            deg = (int*)(ws + OFF_DEG);
    unsigned int*   bmp = (unsigned int*)(ws + OFF_BMP);
    int*            wlc = (int*)(ws + OFF_WL);
    int*            wl  = wlc + 1;
    int*            tpk = (int*)(ws + OFF_TOPK);
    float*          kT32 = (float*)(ws + OFF_KT32);
    float*          tmp  = (float*)(ws + OFF_TMP);

    // zero range: deg + bmp + wl_cnt = 4,325,392 B = 270337 uint4 (done inside k_prep)
    k_prep<<<1024, 256, 0, stream>>>(x, bq, bk, Wq, Wk, Wg,
                                     qh, ql, kh, kl, kT32, h,
                                     (uint4*)(ws + OFF_DEG), 270337);
    k_score<<<1024, 256, 0, stream>>>(qh, ql, kh, kl, bk, bmp, tpk, wlc, wl);
    k_repair<<<1024, 256, 0, stream>>>(x, bq, Wq, kT32, tpk, wlc, wl, bmp);
    k_deg<<<128, 256, 0, stream>>>(bmp, deg);
    k_gather<<<32768, 128, 0, stream>>>(h, bg, deg, bmp, tmp);
    k_transpose<<<dim3(32, 4, 32), 256, 0, stream>>>(tmp, out);
}

// Round 9
// 257.362 us; speedup vs baseline: 1.4756x; 1.0006x over previous
//
#include <hip/hip_runtime.h>

#define NBATCH 32
#define NN     1024     // d_model = number of nodes
#define NF     128      // win_size = node feature dim
#define NDG    64       // graph embed dim
#define TOPK   15

// ---------------- workspace layout (bytes) ----------------
#define OFF_QH    ((size_t)0)            // bf16-hi q [32][1024][64]  4 MiB
#define OFF_QL    ((size_t)4194304)      // bf16-lo q                 4 MiB
#define OFF_KH    ((size_t)8388608)      // bf16-hi k                 4 MiB
#define OFF_KL    ((size_t)12582912)     // bf16-lo k                 4 MiB
#define OFF_H     ((size_t)16777216)     // f32 [32][1024][128]      16 MiB
#define OFF_DEG   ((size_t)33554432)     // i32 [32][1024]          128 KiB
#define OFF_BMP   ((size_t)33685504)     // u32 [32][1024][32]        4 MiB
#define OFF_WL    ((size_t)37879808)     // wl_cnt + wl[32767]      128 KiB
#define OFF_TOPK  ((size_t)38010880)     // i32 [32][1024][16]        2 MiB
#define OFF_KT32  ((size_t)40239104)     // f32 [32][64][1024]        8 MiB (k for repair)
#define OFF_TMP   ((size_t)0)            // f32 [32][1024][128]      16 MiB (overlaps QH..KL, dead by then)

typedef short s8v  __attribute__((ext_vector_type(8)));   // 8 bf16 (4 VGPRs) MFMA operand
typedef float f4v  __attribute__((ext_vector_type(4)));   // MFMA accumulator
typedef unsigned short us8v __attribute__((ext_vector_type(8)));

__device__ inline unsigned short bf16_rne(float f) {
    unsigned u = __float_as_uint(f);
    return (unsigned short)((u + 0x7FFFu + ((u >> 16) & 1u)) >> 16);
}
__device__ inline float bf16_tof(unsigned short h) { return __uint_as_float(((unsigned)h) << 16); }

// monotone 22-bit code for f32 score in window [-4, 4): sign + 5-bit biased exp + 16-bit mantissa
__device__ inline unsigned pack22(float s) {
    unsigned u   = __float_as_uint(s);
    int      mag = (int)(u & 0x7FFFFFFFu);
    int      t   = mag - 0x38800000;                 // bias at 2^-14
    t = t < 0 ? 0 : (t > 0x07FFFFFF ? 0x07FFFFFF : t);
    unsigned ts = (unsigned)t >> 6;                  // 21 bits
    return ((int)u < 0) ? (0x1FFFFFu - ts) : (0x200000u | ts);
}
__device__ inline float dec22(unsigned val22) {
    bool pos = (val22 & 0x200000u) != 0;
    unsigned ts = pos ? (val22 & 0x1FFFFFu) : (0x1FFFFFu - (val22 & 0x1FFFFFu));
    float f = __uint_as_float((ts << 6) + 0x38800000u);
    return pos ? f : -f;
}

// Fused: zero bmp/deg/wl_cnt + q,k f32 + bf16 hi/lo splits + kT32 (repair) + h = nf@Wg.T.
// 1-D grid 1024, block 256, XCD-swizzled so batch b lives on XCD b/4 (matches k_score/k_gather:
// per-XCD working set 4 batches ~ 2 MiB < 4 MiB L2, and writes stay L2-resident for k_score).
__global__ __launch_bounds__(256) void k_prep(
    const float* __restrict__ x, const float* __restrict__ bq, const float* __restrict__ bk,
    const float* __restrict__ Wq, const float* __restrict__ Wk,
    const float* __restrict__ Wg,
    unsigned short* __restrict__ qh, unsigned short* __restrict__ ql,
    unsigned short* __restrict__ kh, unsigned short* __restrict__ kl,
    float* __restrict__ kT32,
    float* __restrict__ h,
    uint4* __restrict__ zbase, int zn)
{
    __shared__ float xs[64 * 129];   // xs[node][f], pad 129 -> conflict-free
    const int t = threadIdx.x;
    const int l = t & 63;
    const int w = t >> 6;
    const int uw = __builtin_amdgcn_readfirstlane(w);
    // XCD swizzle: lid contiguous per XCD (XCD = bid%8 round-robin assumption, T1)
    const int bid = blockIdx.x;                       // 0..1023
    const int lid = (bid & 7) * 128 + (bid >> 3);     // bijective
    const int b    = lid >> 5;                        // batch: 4 per XCD
    const int half = (lid >> 4) & 1;
    const int n0   = (lid & 15) * 64;

    // --- zero phase (deg + bmp + wl_cnt), grid-stride over 1024 blocks ---
    {
        int lid0 = bid * 256 + t;   // 0..262143
        for (int i = lid0; i < zn; i += 262144)
            zbase[i] = make_uint4(0u, 0u, 0u, 0u);
    }

    {   // xs[node][f] = x[b][f][n0+node]  (coalesced over node)
        const int j = t & 63, fg = t >> 6;
        for (int ff = 0; ff < 32; ++ff) {
            int f = fg + ff * 4;
            xs[j * 129 + f] = x[((size_t)b * NF + f) * NN + n0 + j];
        }
    }
    __syncthreads();

    // --- q/k phase (f32, 8 d-dims per wave) ---
    {
        const int d0 = half * 32 + uw * 8;
        float accq[8], acck[8];
        #pragma unroll
        for (int dd = 0; dd < 8; ++dd) {
            accq[dd] = bq[d0 + dd];
            acck[dd] = bk[d0 + dd];
        }
        for (int fc = 0; fc < 32; ++fc) {
            float x0 = xs[l * 129 + fc * 4 + 0];
            float x1 = xs[l * 129 + fc * 4 + 1];
            float x2 = xs[l * 129 + fc * 4 + 2];
            float x3 = xs[l * 129 + fc * 4 + 3];
            #pragma unroll
            for (int dd = 0; dd < 8; ++dd) {
                int d = d0 + dd;   // uniform -> scalar loads of weights
                const float* wq = &Wq[d * NF + fc * 4];
                const float* wk = &Wk[d * NF + fc * 4];
                accq[dd] += x0 * wq[0] + x1 * wq[1] + x2 * wq[2] + x3 * wq[3];
                acck[dd] += x0 * wk[0] + x1 * wk[1] + x2 * wk[2] + x3 * wk[3];
            }
        }
        // k f32 [d][n] for repair (coalesced over lane)
        #pragma unroll
        for (int dd = 0; dd < 8; ++dd)
            kT32[((size_t)b * NDG + d0 + dd) * NN + n0 + l] = acck[dd];
        // bf16 hi/lo splits, [n][d] layout
        us8v qh0, ql0, kh0, kl0;
        #pragma unroll
        for (int dd = 0; dd < 8; ++dd) {
            unsigned short h1 = bf16_rne(accq[dd]);
            unsigned short l1 = bf16_rne(accq[dd] - bf16_tof(h1));
            unsigned short h2 = bf16_rne(acck[dd]);
            unsigned short l2 = bf16_rne(acck[dd] - bf16_tof(h2));
            qh0[dd] = h1; ql0[dd] = l1; kh0[dd] = h2; kl0[dd] = l2;
        }
        size_t nb = ((size_t)b * NN + n0 + l) * NDG + d0;
        *(us8v*)&qh[nb] = qh0;
        *(us8v*)&ql[nb] = ql0;
        *(us8v*)&kh[nb] = kh0;
        *(us8v*)&kl[nb] = kl0;
    }

    // --- h phase (f32, 16 out-features per wave; this block covers f' in [half*64, half*64+64)) ---
    {
        const int fp0 = half * 64 + uw * 16;
        float acc[16];
        #pragma unroll
        for (int i = 0; i < 16; ++i) acc[i] = 0.f;
        for (int fc = 0; fc < 32; ++fc) {
            float x0 = xs[l * 129 + fc * 4 + 0];
            float x1 = xs[l * 129 + fc * 4 + 1];
            float x2 = xs[l * 129 + fc * 4 + 2];
            float x3 = xs[l * 129 + fc * 4 + 3];
            #pragma unroll
            for (int ff = 0; ff < 16; ++ff) {
                const float* wg = &Wg[(fp0 + ff) * NF + fc * 4];
                acc[ff] += x0 * wg[0] + x1 * wg[1] + x2 * wg[2] + x3 * wg[3];
            }
        }
        __syncthreads();   // everyone done reading xs
        #pragma unroll
        for (int ff = 0; ff < 16; ++ff) xs[l * 129 + fp0 + ff] = acc[ff];
        __syncthreads();
        // write h[n][half*64 .. half*64+64) for the 64 nodes
        for (int r = 0; r < 16; ++r) {
            int idx = t + 256 * r;            // 0..4095
            int n = idx >> 6, f = idx & 63;
            h[((size_t)b * NN + n0 + n) * NF + half * 64 + f] = xs[n * 129 + half * 64 + f];
        }
    }
}

// two independent bitonic sort64 chains interleaved (latency overlap); descending, lane l = rank l
__device__ inline void bsort64_2(unsigned& va, unsigned& vb, int l) {
    #pragma unroll
    for (int k = 2; k <= 64; k <<= 1) {
        #pragma unroll
        for (int j = k >> 1; j >= 1; j >>= 1) {
            unsigned pa = (unsigned)__shfl_xor((int)va, j, 64);
            unsigned pb = (unsigned)__shfl_xor((int)vb, j, 64);
            bool tm = ((l & k) == 0) == ((l & j) == 0);
            unsigned ha = va > pa ? va : pa, la = va > pa ? pa : va;
            unsigned hb = vb > pb ? vb : pb, lb = vb > pb ? pb : vb;
            va = tm ? ha : la;
            vb = tm ? hb : lb;
        }
    }
}

// MFMA bf16-split scores, 32 rows/block, all-resident grid, XCD-swizzled (T1).
// B double-buffer with sched_barrier(0) pinning: R5-R8 showed VGPR_Count=72 -> regalloc sank
// the prefetch loads to just-in-time, exposing ~200cy L2 latency per tt-step (the 65us wall).
// The barrier after the prefetch issue forces the 4 loads in flight across the MFMA cluster.
// Guard raw<16 | raw>64 | cell>24 -> dummy set + flagged -> exact k_repair fixes the row.
__global__ __launch_bounds__(256) void k_score(
    const unsigned short* __restrict__ qh, const unsigned short* __restrict__ ql,
    const unsigned short* __restrict__ kh, const unsigned short* __restrict__ kl,
    const float* __restrict__ bk,
    unsigned int* __restrict__ bmp,
    int* __restrict__ topk, int* __restrict__ wl_cnt, int* __restrict__ wl)
{
    __shared__ unsigned slots[32 * 96];   // [row][wave][24], 12 KiB
    __shared__ int      cntw[32 * 4];     // per-(row,wave) survivor count
    const int t = threadIdx.x, l = t & 63, w = t >> 6;   // w in [0,4)
    // XCD swizzle (T1): batch b -> XCD b/4, all 32 row-tiles of a batch co-located
    const int bid = blockIdx.x;                      // 0..1023
    const int lid = (bid & 7) * 128 + (bid >> 3);    // bijective
    const int b = lid >> 5, row0 = (lid & 31) * 32;
    const int m = l & 15, q4 = l >> 4;

    // A fragments: 2 row-groups of 16. A[m][k]: m=lane&15, k=(lane>>4)*8+j
    s8v ah0[2], ah1[2], al0[2], al1[2];
    #pragma unroll
    for (int g = 0; g < 2; ++g) {
        size_t abase = ((size_t)b * NN + row0 + g * 16 + m) * NDG + q4 * 8;
        ah0[g] = *(const s8v*)&qh[abase];
        ah1[g] = *(const s8v*)&qh[abase + 32];
        al0[g] = *(const s8v*)&ql[abase];
        al1[g] = *(const s8v*)&ql[abase + 32];
    }

    // per-row thresholds from q stats: scores ~ N(q.bk/8, |q|^2/64); t = mean + 1.8*std.
    // Tr holds 8*t_m so the filter compares raw MFMA acc (pre-0.125 scale) directly.
    float Tr[2][4];
    #pragma unroll
    for (int g = 0; g < 2; ++g) {
        float ssq = 0.f, smn = 0.f;
        #pragma unroll
        for (int j = 0; j < 8; ++j) {
            float q0 = bf16_tof(((us8v)ah0[g])[j]) + bf16_tof(((us8v)al0[g])[j]);
            float q1 = bf16_tof(((us8v)ah1[g])[j]) + bf16_tof(((us8v)al1[g])[j]);
            float b0 = bk[q4 * 8 + j];
            float b1 = bk[q4 * 8 + 32 + j];
            ssq += q0 * q0 + q1 * q1;
            smn += q0 * b0 + q1 * b1;
        }
        ssq += __shfl_xor(ssq, 16, 64); ssq += __shfl_xor(ssq, 32, 64);
        smn += __shfl_xor(smn, 16, 64); smn += __shfl_xor(smn, 32, 64);
        float t8 = smn + 1.8f * __builtin_sqrtf(ssq);   // 8 * (0.125*smn + 0.225*sqrt(ssq))
        #pragma unroll
        for (int r = 0; r < 4; ++r)
            Tr[g][r] = __shfl(t8, 4 * q4 + r, 64);
    }

    const int colbase = w * 256;
    int basec[2][4] = {{0,0,0,0},{0,0,0,0}};

    // B double-buffer: prefetch tt+1 while computing tt; sched_barrier pins issue order.
    s8v Bh0[2], Bh1[2], Bl0[2], Bl1[2];
    {
        size_t bb = ((size_t)b * NN + colbase + m) * NDG + q4 * 8;
        Bh0[0] = *(const s8v*)&kh[bb];
        Bh1[0] = *(const s8v*)&kh[bb + 32];
        Bl0[0] = *(const s8v*)&kl[bb];
        Bl1[0] = *(const s8v*)&kl[bb + 32];
    }
    #pragma unroll
    for (int tt = 0; tt < 16; ++tt) {
        const int cur = tt & 1;
        if (tt < 15) {
            size_t bb = ((size_t)b * NN + colbase + (tt + 1) * 16 + m) * NDG + q4 * 8;
            Bh0[cur ^ 1] = *(const s8v*)&kh[bb];
            Bh1[cur ^ 1] = *(const s8v*)&kh[bb + 32];
            Bl0[cur ^ 1] = *(const s8v*)&kl[bb];
            Bl1[cur ^ 1] = *(const s8v*)&kl[bb + 32];
        }
        // pin: prefetch loads must issue before the MFMA cluster below (prevents regalloc
        // sinking them to just-in-time, which exposed ~200cy L2 latency per tt-step).
        __builtin_amdgcn_sched_barrier(0);
        const int col = colbase + tt * 16 + m;
        #pragma unroll
        for (int g = 0; g < 2; ++g) {
            f4v acc = {0.f, 0.f, 0.f, 0.f};
            acc = __builtin_amdgcn_mfma_f32_16x16x32_bf16(al0[g], Bl0[cur], acc, 0, 0, 0);
            acc = __builtin_amdgcn_mfma_f32_16x16x32_bf16(al1[g], Bl1[cur], acc, 0, 0, 0);
            acc = __builtin_amdgcn_mfma_f32_16x16x32_bf16(ah0[g], Bl0[cur], acc, 0, 0, 0);
            acc = __builtin_amdgcn_mfma_f32_16x16x32_bf16(ah1[g], Bl1[cur], acc, 0, 0, 0);
            acc = __builtin_amdgcn_mfma_f32_16x16x32_bf16(al0[g], Bh0[cur], acc, 0, 0, 0);
            acc = __builtin_amdgcn_mfma_f32_16x16x32_bf16(al1[g], Bh1[cur], acc, 0, 0, 0);
            acc = __builtin_amdgcn_mfma_f32_16x16x32_bf16(ah0[g], Bh0[cur], acc, 0, 0, 0);
            acc = __builtin_amdgcn_mfma_f32_16x16x32_bf16(ah1[g], Bh1[cur], acc, 0, 0, 0);
            // C/D: col=lane&15, row=(lane>>4)*4+reg. Ballot-compact survivors per (row, wave).
            #pragma unroll
            for (int r = 0; r < 4; ++r) {
                const int rloc = g * 16 + q4 * 4 + r;      // local row 0..31
                const int grow = row0 + rloc;
                bool p = (acc[r] >= Tr[g][r]) && (col != grow);
                unsigned long long mk = __ballot(p);
                unsigned w16 = (unsigned)(mk >> (q4 * 16)) & 0xFFFFu;
                int idx = basec[g][r] + __popc(w16 & ((1u << m) - 1u));
                if (p && idx < 24) {
                    float s = acc[r] * 0.125f;
                    slots[rloc * 96 + w * 24 + idx] = (pack22(s) << 10) | (unsigned)(1023 - col);
                }
                basec[g][r] += __popc(w16);
            }
        }
    }
    // per-(row,wave) raw counts (overflow detectable: >24)
    if (m == 0) {
        #pragma unroll
        for (int g = 0; g < 2; ++g)
            #pragma unroll
            for (int r = 0; r < 4; ++r)
                cntw[(g * 16 + q4 * 4 + r) * 4 + w] = basec[g][r];
    }
    __syncthreads();

    // wave w merges rows [8w, 8w+8) as 4 pairs
    #pragma unroll
    for (int pp = 0; pp < 4; ++pp) {
        const int rA = w * 8 + 2 * pp, rB = rA + 1;
        int a0 = cntw[rA * 4 + 0], a1 = cntw[rA * 4 + 1], a2 = cntw[rA * 4 + 2], a3 = cntw[rA * 4 + 3];
        int b0 = cntw[rB * 4 + 0], b1 = cntw[rB * 4 + 1], b2 = cntw[rB * 4 + 2], b3 = cntw[rB * 4 + 3];
        bool ovA = (a0 > 24) || (a1 > 24) || (a2 > 24) || (a3 > 24);
        bool ovB = (b0 > 24) || (b1 > 24) || (b2 > 24) || (b3 > 24);
        int rawA = a0 + a1 + a2 + a3, rawB = b0 + b1 + b2 + b3;
        a0 = a0 > 24 ? 24 : a0; a1 = a1 > 24 ? 24 : a1; a2 = a2 > 24 ? 24 : a2; a3 = a3 > 24 ? 24 : a3;
        b0 = b0 > 24 ? 24 : b0; b1 = b1 > 24 ? 24 : b1; b2 = b2 > 24 ? 24 : b2; b3 = b3 > 24 ? 24 : b3;
        int PA1 = a0, PA2 = a0 + a1, PA3 = a0 + a1 + a2, CA = PA3 + a3;
        int PB1 = b0, PB2 = b0 + b1, PB3 = b0 + b1 + b2, CB = PB3 + b3;
        bool fbA = ovA || rawA < 16 || rawA > 64;
        bool fbB = ovB || rawB < 16 || rawB > 64;

        int jA = (l >= PA1) + (l >= PA2) + (l >= PA3);
        int jB = (l >= PB1) + (l >= PB2) + (l >= PB3);
        int baseA = jA == 0 ? 0 : (jA == 1 ? PA1 : (jA == 2 ? PA2 : PA3));
        int baseB = jB == 0 ? 0 : (jB == 1 ? PB1 : (jB == 2 ? PB2 : PB3));
        unsigned cva = (l < CA) ? slots[rA * 96 + jA * 24 + (l - baseA)] : 0u;
        unsigned cvb = (l < CB) ? slots[rB * 96 + jB * 24 + (l - baseB)] : 0u;
        bsort64_2(cva, cvb, l);   // lane l = rank-l value (descending)

        #pragma unroll
        for (int rr = 0; rr < 2; ++rr) {
            const int grow = row0 + (rr == 0 ? rA : rB);
            unsigned res   = rr == 0 ? cva : cvb;
            const bool fb  = rr == 0 ? fbA : fbB;

            unsigned r14 = (unsigned)__shfl((int)res, 14, 64);
            unsigned r15 = (unsigned)__shfl((int)res, 15, 64);
            bool flagged;
            if (fb) {
                flagged = true;
            } else {
                float s15 = dec22(r14 >> 10), s16 = dec22(r15 >> 10);
                unsigned e15 = (__float_as_uint(fabsf(s15)) >> 23) & 255u;
                unsigned e16 = (__float_as_uint(fabsf(s16)) >> 23) & 255u;
                unsigned e = e15 > e16 ? e15 : e16;
                float qq = __uint_as_float((e - 17) << 23);    // 22-bit code quantum
                flagged = (s15 - s16) < (4.f * qq + 1e-4f);
            }
            if (l < 15) {
                int col = fb ? ((grow + 1 + l) & 1023)          // dummy distinct non-self set
                             : (1023 - (int)(res & 1023u));
                atomicOr(&bmp[((size_t)b * NN + col) * 32 + (grow >> 5)], 1u << (grow & 31));
                if (flagged) topk[(b * NN + grow) * 16 + l] = col;
            }
            if (l == 0 && flagged) {
                int idx = atomicAdd(wl_cnt, 1);
                if (idx < 32767) wl[idx] = b * NN + grow;
            }
        }
    }
}

// exact re-selection for worklist rows; patches bitmap by set-diff (deg derived later).
// grid 1024, block 256 (4 waves per ROW): q of the flagged row recomputed on the fly in f64
// from x + f32 Wq (products exact); scores = f64 accumulation over f32 k (kT32).
// Selection: 15 block-wide argmax iterations (wave shfl-reduce -> 4 LDS candidates -> pick).
__global__ __launch_bounds__(256) void k_repair(
    const float* __restrict__ x, const float* __restrict__ bq, const float* __restrict__ Wq,
    const float* __restrict__ kT32,
    const int* __restrict__ topk, const int* __restrict__ wl_cnt, const int* __restrict__ wl,
    unsigned int* __restrict__ bmp)
{
    const int t = threadIdx.x, l = t & 63, w = t >> 6;
    __shared__ float  xrow[128];
    __shared__ double qld[64];
    __shared__ double cmax[4];
    __shared__ int    cidx[4];
    __shared__ int    oldset[15], newset[15];
    const double NEGINF = -__builtin_inf();
    int n = wl_cnt[0]; if (n > 32767) n = 32767;

    for (int i = blockIdx.x; i < n; i += 1024) {
        int rg = wl[i];
        int b = rg >> 10, row = rg & 1023;

        __syncthreads();   // guard shared reuse across grid-stride iterations
        if (t < 128) xrow[t] = x[((size_t)b * NF + t) * NN + row];
        if (t < 15) oldset[t] = topk[(b * NN + row) * 16 + t];
        __syncthreads();
        if (t < 64) {   // q[d] for this row, f64 accumulation of f32 products
            double acc = (double)bq[t];
            const float* wq = &Wq[t * NF];
            for (int f = 0; f < 128; ++f)
                acc += (double)xrow[f] * (double)wq[f];
            qld[t] = acc;
        }
        __syncthreads();

        const float* kb = &kT32[(size_t)b * NDG * NN];
        const int base = l + 256 * w;
        const int c0 = base, c1 = base + 64, c2 = base + 128, c3 = base + 192;
        double s0 = 0.0, s1 = 0.0, s2 = 0.0, s3 = 0.0;
        float b0 = kb[c0], b1 = kb[c1], b2 = kb[c2], b3 = kb[c3];
        for (int d = 0; d < 64; ++d) {
            float n0, n1, n2, n3;
            if (d < 63) {
                const float* kr = kb + (size_t)(d + 1) * NN;
                n0 = kr[c0]; n1 = kr[c1]; n2 = kr[c2]; n3 = kr[c3];
            }
            double qd = qld[d];
            s0 += qd * (double)b0; s1 += qd * (double)b1;
            s2 += qd * (double)b2; s3 += qd * (double)b3;
            if (d < 63) { b0 = n0; b1 = n1; b2 = n2; b3 = n3; }
        }
        if (c0 == row) s0 = NEGINF;
        if (c1 == row) s1 = NEGINF;
        if (c2 == row) s2 = NEGINF;
        if (c3 == row) s3 = NEGINF;

        for (int it = 0; it < 15; ++it) {
            double lv = NEGINF; int lc = 0x7fffffff;
            if (s0 > lv) { lv = s0; lc = c0; }
            if (s1 > lv) { lv = s1; lc = c1; }
            if (s2 > lv) { lv = s2; lc = c2; }
            if (s3 > lv) { lv = s3; lc = c3; }
            #pragma unroll
            for (int off = 1; off < 64; off <<= 1) {
                double ov = __shfl_xor(lv, off, 64);
                int    oc = __shfl_xor(lc, off, 64);
                if (ov > lv || (ov == lv && oc < lc)) { lv = ov; lc = oc; }
            }
            if (l == 0) { cmax[w] = lv; cidx[w] = lc; }
            __syncthreads();
            if (t == 0) {
                double bv = cmax[0]; int bc = cidx[0];
                #pragma unroll
                for (int ww = 1; ww < 4; ++ww)
                    if (cmax[ww] > bv || (cmax[ww] == bv && cidx[ww] < bc)) { bv = cmax[ww]; bc = cidx[ww]; }
                newset[it] = bc;
            }
            __syncthreads();
            int bc = newset[it];
            if (c0 == bc) s0 = NEGINF;
            if (c1 == bc) s1 = NEGINF;
            if (c2 == bc) s2 = NEGINF;
            if (c3 == bc) s3 = NEGINF;
        }

        if (t < 15) {
            int cn = newset[t];
            bool found = false;
            #pragma unroll
            for (int j = 0; j < 15; ++j) found = found || (oldset[j] == cn);
            if (!found)
                atomicOr(&bmp[((size_t)b * NN + cn) * 32 + (row >> 5)], 1u << (row & 31));
            int co = oldset[t];
            found = false;
            #pragma unroll
            for (int j = 0; j < 15; ++j) found = found || (newset[j] == co);
            if (!found)
                atomicAnd(&bmp[((size_t)b * NN + co) * 32 + (row >> 5)], ~(1u << (row & 31)));
        }
    }
}

// deg[b][n] = popcount of bmp row (number of rows that selected node n). grid 128, block 256.
__global__ __launch_bounds__(256) void k_deg(const unsigned int* __restrict__ bmp,
                                             int* __restrict__ deg)
{
    int i = blockIdx.x * 256 + threadIdx.x;   // 0..32767 over (b,n)
    const uint4* p = (const uint4*)(bmp + (size_t)i * 32);
    int s = 0;
    #pragma unroll
    for (int j = 0; j < 8; ++j) {
        uint4 v = p[j];
        s += __popc(v.x) + __popc(v.y) + __popc(v.z) + __popc(v.w);
    }
    deg[i] = s;
}

// gather per target via compacted LDS edge list + LDS norm table (dinv folded here).
// 1-D grid 32768, block 128 (f = thread), XCD-swizzled: batch b on XCD b/4 (h working set
// 4 x 512 KB = 2 MiB per XCD < L2). Edge loop 4-way unrolled for load ILP.
__global__ __launch_bounds__(128) void k_gather(
    const float* __restrict__ h, const float* __restrict__ bg,
    const int* __restrict__ deg, const unsigned int* __restrict__ bmp,
    float* __restrict__ tmp)
{
    __shared__ int list[1024];
    __shared__ float nrm[1024];
    __shared__ int scnt;
    const int bid = blockIdx.x;                        // 0..32767
    const int lid = (bid & 7) * 4096 + (bid >> 3);     // bijective, XCD chunks
    const int b = lid >> 10, tgt = lid & 1023;
    const int t = threadIdx.x;
    if (t < 32) {
        unsigned word = bmp[((size_t)b * NN + tgt) * 32 + t];
        int pc = __popc(word);
        int pre = pc;
        #pragma unroll
        for (int d = 1; d < 32; d <<= 1) {
            int o = __shfl_up(pre, d, 32);
            if (t >= d) pre += o;
        }
        if (t == 31) scnt = pre;
        int idx = pre - pc;
        while (word) {
            int s = __ffs(word) - 1;
            word &= word - 1;
            list[idx++] = t * 32 + s;
        }
    }
    __syncthreads();
    const int cnt = scnt;
    for (int e = t; e < cnt; e += 128)
        nrm[e] = rsqrtf((float)(deg[b * NN + list[e]] + 2));
    __syncthreads();
    const int f = t;
    float dt = rsqrtf((float)(deg[b * NN + tgt] + 2));
    float a0 = 0.f, a1 = 0.f, a2 = 0.f, a3 = 0.f;
    int e = 0;
    for (; e + 4 <= cnt; e += 4) {
        a0 += h[((size_t)b * NN + list[e + 0]) * NF + f] * nrm[e + 0];
        a1 += h[((size_t)b * NN + list[e + 1]) * NF + f] * nrm[e + 1];
        a2 += h[((size_t)b * NN + list[e + 2]) * NF + f] * nrm[e + 2];
        a3 += h[((size_t)b * NN + list[e + 3]) * NF + f] * nrm[e + 3];
    }
    for (; e < cnt; ++e)
        a0 += h[((size_t)b * NN + list[e]) * NF + f] * nrm[e];
    float acc = 2.0f * dt * h[((size_t)b * NN + tgt) * NF + f] + ((a0 + a1) + (a2 + a3));
    tmp[((size_t)b * NN + tgt) * NF + f] = bg[f] + dt * acc;
}

// [b][n][f] -> [b][f][n]. grid (32, 4, 32), block 256.
__global__ __launch_bounds__(256) void k_transpose(const float* __restrict__ tmp,
                                                   float* __restrict__ out)
{
    __shared__ float tile[32][33];
    const int t = threadIdx.x;
    const int n0 = blockIdx.x * 32, f0 = blockIdx.y * 32, b = blockIdx.z;
    const int c = t & 31, rb = t >> 5;
    #pragma unroll
    for (int i = 0; i < 4; ++i) {
        int r = rb + i * 8;
        tile[r][c] = tmp[((size_t)b * NN + n0 + r) * NF + f0 + c];
    }
    __syncthreads();
    #pragma unroll
    for (int i = 0; i < 4; ++i) {
        int r = rb + i * 8;
        out[((size_t)b * NF + f0 + r) * NN + n0 + c] = tile[c][r];
    }
}

extern "C" void kernel_launch(void* const* d_in, const int* in_sizes, int n_in,
                              void* d_out, int out_size, void* d_ws, size_t ws_size,
                              hipStream_t stream)
{
    const float* x  = (const float*)d_in[0];
    const float* Wq = (const float*)d_in[1];
    const float* bq = (const float*)d_in[2];
    const float* Wk = (const float*)d_in[3];
    const float* bk = (const float*)d_in[4];
    const float* Wg = (const float*)d_in[5];
    const float* bg = (const float*)d_in[6];
    float* out = (float*)d_out;
    char* ws = (char*)d_ws;

    unsigned short* qh = (unsigned short*)(ws + OFF_QH);
    unsigned short* ql = (unsigned short*)(ws + OFF_QL);
    unsigned short* kh = (unsigned short*)(ws + OFF_KH);
    unsigned short* kl = (unsigned short*)(ws + OFF_KL);
    float*          h   = (float*)(ws + OFF_H);
    int*            deg = (int*)(ws + OFF_DEG);
    unsigned int*   bmp = (unsigned int*)(ws + OFF_BMP);
    int*            wlc = (int*)(ws + OFF_WL);
    int*            wl  = wlc + 1;
    int*            tpk = (int*)(ws + OFF_TOPK);
    float*          kT32 = (float*)(ws + OFF_KT32);
    float*          tmp  = (float*)(ws + OFF_TMP);

    // zero range: deg + bmp + wl_cnt = 4,325,392 B = 270337 uint4 (done inside k_prep)
    k_prep<<<1024, 256, 0, stream>>>(x, bq, bk, Wq, Wk, Wg,
                                     qh, ql, kh, kl, kT32, h,
                                     (uint4*)(ws + OFF_DEG), 270337);
    k_score<<<1024, 256, 0, stream>>>(qh, ql, kh, kl, bk, bmp, tpk, wlc, wl);
    k_repair<<<1024, 256, 0, stream>>>(x, bq, Wq, kT32, tpk, wlc, wl, bmp);
    k_deg<<<128, 256, 0, stream>>>(bmp, deg);
    k_gather<<<32768, 128, 0, stream>>>(h, bg, deg, bmp, tmp);
    k_transpose<<<dim3(32, 4, 32), 256, 0, stream>>>(tmp, out);
}